// Round 10
// baseline (430.978 us; speedup 1.0000x reference)
//
#include <hip/hip_runtime.h>
#include <hip/hip_bf16.h>
#include <cstdint>
#include <cstddef>

typedef short short8 __attribute__((ext_vector_type(8)));
typedef short short4v __attribute__((ext_vector_type(4)));
typedef float f32x4 __attribute__((ext_vector_type(4)));
typedef __hip_bfloat16 bf16;

#define NROW 2048      // S*B rows
#define N1 1536        // [upl(1024); upr(512)]
#define N2 1664        // [wq(512); wk(512); skip(512); wi(8); wf(8); pad(112)]
#define N3 1024        // [wv(512); wo(512)]
#define EPSV 1e-5f
#define NUMSZ ((size_t)32*512*64)

static __device__ __forceinline__ bf16 f2bf(float v){ return __float2bfloat16(v); }
static __device__ __forceinline__ float bfbits2f(short s){
  unsigned u = ((unsigned)(unsigned short)s) << 16;
  float f; __builtin_memcpy(&f, &u, 4); return f;
}
static __device__ __forceinline__ void split_bf(float v, bf16& h, bf16& l){
  h = __float2bfloat16(v);
  l = __float2bfloat16(v - __bfloat162float(h));
}

static __device__ __forceinline__ void gload16(const bf16* g, bf16* l){
  __builtin_amdgcn_global_load_lds(
      (const __attribute__((address_space(1))) void*)(g),
      (__attribute__((address_space(3))) void*)(l), 16, 0, 0);
}

#define MFMA __builtin_amdgcn_mfma_f32_16x16x32_bf16

// ===================== single mega weight/bias pack kernel (vectorized) =====================
// W1: 768 blocks (2 rows each) | W2: 1664 | W3: 1024 | W4: 256 (2 rows) | bias: 1
__global__ __launch_bounds__(256) void pack_all(
    const float* __restrict__ upl, const float* __restrict__ upr,
    const float* __restrict__ wq,  const float* __restrict__ wk,
    const float* __restrict__ skp, const float* __restrict__ wi,
    const float* __restrict__ wf,  const float* __restrict__ wv,
    const float* __restrict__ wo,  const float* __restrict__ dw,
    const float* __restrict__ uplb, const float* __restrict__ uprb,
    const float* __restrict__ wqb,  const float* __restrict__ wkb,
    const float* __restrict__ wib,  const float* __restrict__ wfb,
    const float* __restrict__ wvb,  const float* __restrict__ wob,
    const float* __restrict__ dwb,
    bf16* __restrict__ W1h, bf16* __restrict__ W1l,
    bf16* __restrict__ W2h, bf16* __restrict__ W2l,
    bf16* __restrict__ W3h, bf16* __restrict__ W3l,
    bf16* __restrict__ W4h, bf16* __restrict__ W4l,
    float* __restrict__ b1, float* __restrict__ b2,
    float* __restrict__ b3, float* __restrict__ b4)
{
  int l = blockIdx.y;
  int bx = blockIdx.x;
  if (bx < 768){                        // ---- W1: [upl(1024); upr(512)], K=512, 2 rows/block
    int r = bx*2 + (threadIdx.x >> 7);
    int c4 = threadIdx.x & 127;
    const float* src = (r < 1024) ? upl + ((size_t)l*1024 + r)*512
                                  : upr + ((size_t)l*512 + (r-1024))*512;
    size_t o = ((size_t)l*N1 + r)*512 + c4*4;
    f32x4 v = *(const f32x4*)(src + c4*4);
    short4v hh, ll;
    for (int e=0;e<4;e++){ bf16 h_,l_; split_bf(v[e],h_,l_);
      hh[e] = *(short*)&h_; ll[e] = *(short*)&l_; }
    *(short4v*)(W1h+o) = hh; *(short4v*)(W1l+o) = ll;
  } else if (bx < 2432){                // ---- W2, K=1024
    int r = bx - 768;
    int c4 = threadIdx.x;
    const float* src; float sc = 1.f;
    if (r < 512)        src = wq  + ((size_t)l*512 + r)*1024;
    else if (r < 1024){ src = wk  + ((size_t)l*512 + r-512)*1024; sc = 0.125f; }
    else if (r < 1536)  src = skp + ((size_t)l*512 + r-1024)*1024;
    else if (r < 1544)  src = wi  + ((size_t)l*8   + r-1536)*1024;
    else if (r < 1552)  src = wf  + ((size_t)l*8   + r-1544)*1024;
    else src = nullptr;
    size_t o = ((size_t)l*N2 + r)*1024 + c4*4;
    f32x4 v = src ? *(const f32x4*)(src + c4*4) : (f32x4){0.f,0.f,0.f,0.f};
    short4v hh, ll;
    for (int e=0;e<4;e++){ bf16 h_,l_; split_bf(v[e]*sc,h_,l_);
      hh[e] = *(short*)&h_; ll[e] = *(short*)&l_; }
    *(short4v*)(W2h+o) = hh; *(short4v*)(W2l+o) = ll;
  } else if (bx < 3456){                // ---- W3: [wv; wo], K=1024
    int r = bx - 2432;
    int c4 = threadIdx.x;
    const float* src = (r < 512) ? wv + ((size_t)l*512 + r)*1024
                                 : wo + ((size_t)l*512 + (r-512))*1024;
    size_t o = ((size_t)l*N3 + r)*1024 + c4*4;
    f32x4 v = *(const f32x4*)(src + c4*4);
    short4v hh, ll;
    for (int e=0;e<4;e++){ bf16 h_,l_; split_bf(v[e],h_,l_);
      hh[e] = *(short*)&h_; ll[e] = *(short*)&l_; }
    *(short4v*)(W3h+o) = hh; *(short4v*)(W3l+o) = ll;
  } else if (bx < 3712){                // ---- W4 (down), K=512, 2 rows/block
    int r = (bx - 3456)*2 + (threadIdx.x >> 7);
    int c4 = threadIdx.x & 127;
    const float* src = dw + ((size_t)l*512 + r)*512;
    size_t o = ((size_t)l*512 + r)*512 + c4*4;
    f32x4 v = *(const f32x4*)(src + c4*4);
    short4v hh, ll;
    for (int e=0;e<4;e++){ bf16 h_,l_; split_bf(v[e],h_,l_);
      hh[e] = *(short*)&h_; ll[e] = *(short*)&l_; }
    *(short4v*)(W4h+o) = hh; *(short4v*)(W4l+o) = ll;
  } else {                              // ---- biases
    for (int j = threadIdx.x; j < N1; j += 256)
      b1[l*N1+j] = (j < 1024) ? uplb[l*1024+j] : uprb[l*512+j-1024];
    for (int j = threadIdx.x; j < N2; j += 256){
      float v = 0.f;
      if (j < 512)        v = wqb[l*512+j];
      else if (j < 1024)  v = wkb[l*512+j-512]*0.125f;
      else if (j < 1536)  v = 0.f;
      else if (j < 1544)  v = wib[l*8+j-1536];
      else if (j < 1552)  v = wfb[l*8+j-1544];
      b2[l*N2+j] = v;
    }
    for (int j = threadIdx.x; j < N3; j += 256)
      b3[l*N3+j] = (j < 512) ? wvb[l*512+j] : wob[l*512+j-512];
    for (int j = threadIdx.x; j < 512; j += 256)
      b4[l*512+j] = dwb[l*512+j];
  }
}

// ===================== LDS-staged split-bf16 GEMM core (128x128, 8 waves) =====================
// BK=32, double-buffered, global_load_lds 16B, coalesced staging (4 lanes/64B row)
// + XOR slot swizzle on the GLOBAL column.
static __device__ __forceinline__ void gemm_core(
    bf16* __restrict__ sm,        // 2 bufs x [Ah|Al|Bh|Bl] x 4096 bf16
    int bx, int by,
    const bf16* __restrict__ Ah, const bf16* __restrict__ Al,
    const bf16* __restrict__ Wh, const bf16* __restrict__ Wl,
    const float* __restrict__ bias, float* __restrict__ Cf,
    bf16* __restrict__ Cbh, bf16* __restrict__ Cbl,
    const float* __restrict__ resid, int N, int K, int lda)
{
  int tid = threadIdx.x;
  int lane = tid & 63, w = tid >> 6;
  int wr = w >> 2, wc = w & 3;            // 2 x 4 waves, each 64(M) x 32(N)
  int m0 = by*128, n0 = bx*128;
  int srow = tid >> 2, sslot = tid & 3;   // coalesced: 4 lanes per 64B row
  int gcol = ((sslot ^ (srow & 3)) * 8);  // pre-swizzled global slot
  const bf16* gAh = Ah + (size_t)(m0 + srow)*lda + gcol;
  const bf16* gAl = Al + (size_t)(m0 + srow)*lda + gcol;
  const bf16* gBh = Wh + (size_t)(n0 + srow)*K + gcol;
  const bf16* gBl = Wl + (size_t)(n0 + srow)*K + gcol;

  f32x4 acc[4][2];
  for (int i=0;i<4;i++) for (int j=0;j<2;j++) acc[i][j] = (f32x4){0.f,0.f,0.f,0.f};

  int r = lane & 15, g = lane >> 4;
  int xs = (g ^ (r & 3)) * 8;             // swizzled read slot
  int aoff[4], boff[2];
  for (int mi=0;mi<4;mi++) aoff[mi] = (wr*64 + mi*16 + r)*32 + xs;
  for (int ni=0;ni<2;ni++) boff[ni] = (wc*32 + ni*16 + r)*32 + xs;

  int nt = K >> 5;
#define STAGE_T(base, kk) do{ bf16* _d = sm + (base) + tid*8; \
    gload16(gAh + (kk), _d); \
    gload16(gAl + (kk), _d + 4096); \
    gload16(gBh + (kk), _d + 8192); \
    gload16(gBl + (kk), _d + 12288); }while(0)

  STAGE_T(0, 0);
  asm volatile("s_waitcnt vmcnt(0)" ::: "memory");
  __builtin_amdgcn_s_barrier();

  for (int t = 0; t < nt; ++t){
    int cb = (t & 1) * 16384;
    if (t + 1 < nt) STAGE_T(16384 - cb, (t+1)*32);
    const bf16* sA = sm + cb;
    short8 ah[4], al[4], bh2[2], bl2[2];
    for (int mi=0;mi<4;mi++){
      ah[mi] = *(const short8*)(sA + aoff[mi]);
      al[mi] = *(const short8*)(sA + 4096 + aoff[mi]);
    }
    for (int ni=0;ni<2;ni++){
      bh2[ni] = *(const short8*)(sA + 8192 + boff[ni]);
      bl2[ni] = *(const short8*)(sA + 12288 + boff[ni]);
    }
    for (int mi=0;mi<4;mi++) for (int ni=0;ni<2;ni++)
      acc[mi][ni] = MFMA(ah[mi], bh2[ni], acc[mi][ni],0,0,0);
    for (int mi=0;mi<4;mi++) for (int ni=0;ni<2;ni++)
      acc[mi][ni] = MFMA(al[mi], bh2[ni], acc[mi][ni],0,0,0);
    for (int mi=0;mi<4;mi++) for (int ni=0;ni<2;ni++)
      acc[mi][ni] = MFMA(ah[mi], bl2[ni], acc[mi][ni],0,0,0);
    asm volatile("s_waitcnt vmcnt(0)" ::: "memory");
    __builtin_amdgcn_s_barrier();
  }
#undef STAGE_T

  for (int mi=0;mi<4;mi++) for (int ni=0;ni<2;ni++){
    int col = n0 + wc*32 + ni*16 + r;
    float bv = bias ? bias[col] : 0.f;
    for (int j=0;j<4;j++){
      int row = m0 + wr*64 + mi*16 + g*4 + j;
      float v = acc[mi][ni][j] + bv;
      size_t o = (size_t)row*N + col;
      if (resid) v += resid[o];
      if (Cf) Cf[o] = v;
      if (Cbh) split_bf(v, Cbh[o], Cbl[o]);
    }
  }
}

// ===================== 64x128-tile GEMM core (256 thr, 4 waves, 48KB LDS) =====================
static __device__ __forceinline__ void gemm_core64(
    bf16* __restrict__ sm,        // 2 bufs x [Ah(2048)|Al(2048)|Bh(4096)|Bl(4096)]
    int bx, int by,
    const bf16* __restrict__ Ah, const bf16* __restrict__ Al,
    const bf16* __restrict__ Wh, const bf16* __restrict__ Wl,
    const float* __restrict__ bias, float* __restrict__ Cf,
    bf16* __restrict__ Cbh, bf16* __restrict__ Cbl,
    const float* __restrict__ resid, int N, int K, int lda)
{
  int tid = threadIdx.x;                  // 256 threads, 4 waves
  int lane = tid & 63, w = tid >> 6;      // wave w covers cols w*32..+31
  int m0 = by*64, n0 = bx*128;
  int srow = tid >> 2, sslot = tid & 3;
  int gcol = ((sslot ^ (srow & 3)) * 8);
  const bf16* gAh = Ah + (size_t)(m0 + srow)*lda + gcol;
  const bf16* gAl = Al + (size_t)(m0 + srow)*lda + gcol;
  const bf16* gBh = Wh + (size_t)(n0 + srow)*K + gcol;
  const bf16* gBl = Wl + (size_t)(n0 + srow)*K + gcol;
  size_t pstr = (size_t)64*K;             // B rows 64..127

  f32x4 acc[4][2];
  for (int i=0;i<4;i++) for (int j=0;j<2;j++) acc[i][j] = (f32x4){0.f,0.f,0.f,0.f};

  int r = lane & 15, g = lane >> 4;
  int xs = (g ^ (r & 3)) * 8;
  int aoff[4], boff[2];
  for (int mi=0;mi<4;mi++) aoff[mi] = (mi*16 + r)*32 + xs;
  for (int ni=0;ni<2;ni++) boff[ni] = (w*32 + ni*16 + r)*32 + xs;

  int nt = K >> 5;
#define STAGE64(base, kk) do{ bf16* _d = sm + (base) + tid*8; \
    gload16(gAh + (kk), _d); \
    gload16(gAl + (kk), _d + 2048); \
    gload16(gBh + (kk), _d + 4096);  gload16(gBh + (kk) + pstr, _d + 6144); \
    gload16(gBl + (kk), _d + 8192);  gload16(gBl + (kk) + pstr, _d + 10240); }while(0)

  STAGE64(0, 0);
  asm volatile("s_waitcnt vmcnt(0)" ::: "memory");
  __builtin_amdgcn_s_barrier();

  for (int t = 0; t < nt; ++t){
    int cb = (t & 1) * 12288;
    if (t + 1 < nt) STAGE64(12288 - cb, (t+1)*32);
    const bf16* sA = sm + cb;
    short8 ah[4], al[4], bh2[2], bl2[2];
    for (int mi=0;mi<4;mi++){
      ah[mi] = *(const short8*)(sA + aoff[mi]);
      al[mi] = *(const short8*)(sA + 2048 + aoff[mi]);
    }
    for (int ni=0;ni<2;ni++){
      bh2[ni] = *(const short8*)(sA + 4096 + boff[ni]);
      bl2[ni] = *(const short8*)(sA + 8192 + boff[ni]);
    }
    for (int mi=0;mi<4;mi++) for (int ni=0;ni<2;ni++)
      acc[mi][ni] = MFMA(ah[mi], bh2[ni], acc[mi][ni],0,0,0);
    for (int mi=0;mi<4;mi++) for (int ni=0;ni<2;ni++)
      acc[mi][ni] = MFMA(al[mi], bh2[ni], acc[mi][ni],0,0,0);
    for (int mi=0;mi<4;mi++) for (int ni=0;ni<2;ni++)
      acc[mi][ni] = MFMA(ah[mi], bl2[ni], acc[mi][ni],0,0,0);
    asm volatile("s_waitcnt vmcnt(0)" ::: "memory");
    __builtin_amdgcn_s_barrier();
  }
#undef STAGE64

  for (int mi=0;mi<4;mi++) for (int ni=0;ni<2;ni++){
    int col = n0 + w*32 + ni*16 + r;
    float bv = bias ? bias[col] : 0.f;
    for (int j=0;j<4;j++){
      int row = m0 + mi*16 + g*4 + j;
      float v = acc[mi][ni][j] + bv;
      size_t o = (size_t)row*N + col;
      if (resid) v += resid[o];
      if (Cf) Cf[o] = v;
      if (Cbh) split_bf(v, Cbh[o], Cbl[o]);
    }
  }
}

// standalone small GEMM (64x128): 1D grid (divisible by 8), XCD swizzle
__global__ __launch_bounds__(256) void gemm_s64(
    const bf16* __restrict__ Ah, const bf16* __restrict__ Al,
    const bf16* __restrict__ Wh, const bf16* __restrict__ Wl,
    const float* __restrict__ bias, float* __restrict__ Cf,
    bf16* __restrict__ Cbh, bf16* __restrict__ Cbl,
    const float* __restrict__ resid, int N, int K, int lda, int nbx)
{
  __shared__ bf16 sm[2*12288];
  int id = blockIdx.x;
  int cpx = gridDim.x >> 3;
  int swz = (id & 7)*cpx + (id >> 3);
  int by = swz / nbx, bx = swz - by*nbx;
  gemm_core64(sm, bx, by, Ah, Al, Wh, Wl, bias, Cf, Cbh, Cbl, resid, N, K, lda);
}

// fused gemm2+gemm3 (both K=1024): bx<13 -> set2 (N2), else set3 (N3, A=c1 via lda)
__global__ __launch_bounds__(512) void gemm23(
    const bf16* __restrict__ A2h, const bf16* __restrict__ A2l,
    const bf16* __restrict__ W2h, const bf16* __restrict__ W2l,
    const float* __restrict__ b2,
    bf16* __restrict__ c2h, bf16* __restrict__ c2l,
    const bf16* __restrict__ A3h, const bf16* __restrict__ A3l,
    const bf16* __restrict__ W3h, const bf16* __restrict__ W3l,
    const float* __restrict__ b3,
    bf16* __restrict__ c3h, bf16* __restrict__ c3l)
{
  __shared__ bf16 sm[2*4*4096];
  int id = blockIdx.x;
  int cpx = gridDim.x >> 3;          // 336/8 = 42
  int swz = (id & 7)*cpx + (id >> 3);
  int by = swz / 21, bx = swz - by*21;
  if (bx < 13)
    gemm_core(sm, bx, by, A2h, A2l, W2h, W2l, b2, nullptr, c2h, c2l,
              nullptr, N2, 1024, 1024);
  else
    gemm_core(sm, bx-13, by, A3h, A3l, W3h, W3l, b3, nullptr, c3h, c3l,
              nullptr, N3, 1024, N1);
}

// ===================== LayerNorm (fp32 in -> hi/lo bf16 out) =====================
__global__ __launch_bounds__(256) void ln_kernel(const float* __restrict__ x,
    const float* __restrict__ g, const float* __restrict__ bt,
    bf16* __restrict__ xnh, bf16* __restrict__ xnl)
{
  int row = blockIdx.x, t = threadIdx.x;
  float v0 = x[(size_t)row*512 + t], v1 = x[(size_t)row*512 + 256 + t];
  float s = v0 + v1, ss = v0*v0 + v1*v1;
  for (int m=1; m<64; m<<=1){ s += __shfl_xor(s,m); ss += __shfl_xor(ss,m); }
  __shared__ float sh[8];
  int w = t >> 6, lane = t & 63;
  if (lane == 0){ sh[w] = s; sh[4+w] = ss; }
  __syncthreads();
  s = sh[0]+sh[1]+sh[2]+sh[3]; ss = sh[4]+sh[5]+sh[6]+sh[7];
  float mu = s*(1.f/512.f), var = ss*(1.f/512.f) - mu*mu;
  float rs = rsqrtf(var + EPSV);
  float y0 = (v0-mu)*rs*g[t]     + bt[t];
  float y1 = (v1-mu)*rs*g[256+t] + bt[256+t];
  split_bf(y0, xnh[(size_t)row*512 + t],       xnl[(size_t)row*512 + t]);
  split_bf(y1, xnh[(size_t)row*512 + 256 + t], xnl[(size_t)row*512 + 256 + t]);
}

// ===================== causal conv + silu; reads c1 hi/lo, writes x_c hi/lo only =====================
__global__ __launch_bounds__(256) void conv_kernel(
    const bf16* __restrict__ c1h, const bf16* __restrict__ c1l,
    const float* __restrict__ cw, const float* __restrict__ cb,
    bf16* __restrict__ xch, bf16* __restrict__ xcl)
{
  int row = blockIdx.x;
  size_t rb = (size_t)row*N1;
  float w0=cw[0], w1=cw[1], w2=cw[2], w3=cw[3], bb=cb[0];
  int j0 = threadIdx.x*4;          // 0..1023, 4 consecutive outputs
  float x[7];
  for (int k=0;k<3;k++){
    int j = j0-3+k;
    x[k] = (j>=0) ? (bfbits2f(*(const short*)(c1h+rb+j)) +
                     bfbits2f(*(const short*)(c1l+rb+j))) : 0.f;
  }
  short4v h4 = *(const short4v*)(c1h+rb+j0);
  short4v l4 = *(const short4v*)(c1l+rb+j0);
  for (int k=0;k<4;k++) x[3+k] = bfbits2f(h4[k]) + bfbits2f(l4[k]);
  for (int i=0;i<4;i++){
    float y = bb + w0*x[i] + w1*x[i+1] + w2*x[i+2] + w3*x[i+3];
    float sg = 1.f/(1.f + __expf(-y));
    size_t o = (size_t)row*1024 + j0 + i;
    split_bf(y*sg, xch[o], xcl[o]);
  }
}

// ===================== V transpose to (bh, d, s), hi/lo bf16 =====================
__global__ __launch_bounds__(512) void vtrans_kernel(
    const bf16* __restrict__ c3h, const bf16* __restrict__ c3l,
    bf16* __restrict__ vTh, bf16* __restrict__ vTl)
{
  int bh = blockIdx.y, b = bh >> 3, h = bh & 7;
  int d0 = blockIdx.x*8;
  int s = threadIdx.x;
  size_t i = (size_t)(s*4+b)*N3 + h*64 + d0;
  short4v h0 = *(const short4v*)(c3h+i), h1 = *(const short4v*)(c3h+i+4);
  short4v l0 = *(const short4v*)(c3l+i), l1 = *(const short4v*)(c3l+i+4);
  for (int dd=0; dd<4; dd++){
    size_t o = ((size_t)bh*64 + d0+dd)*512 + s;
    *(short*)(vTh+o) = h0[dd];
    *(short*)(vTl+o) = l0[dd];
  }
  for (int dd=0; dd<4; dd++){
    size_t o = ((size_t)bh*64 + d0+4+dd)*512 + s;
    *(short*)(vTh+o) = h1[dd];
    *(short*)(vTl+o) = l1[dd];
  }
}

// ===================== fused attention (split-K): scan + QK^T -> decay/mask -> PV + den =====================
// grid (32, 32 bh): x = (tb<<1)|half; each half handles sb = half, half+2, ...
// Partial num -> num + half*NUMSZ; den partials -> denp[bt*8 + half*4 + w].
__global__ __launch_bounds__(256) void attn_kernel(
    const bf16* __restrict__ c2h, const bf16* __restrict__ c2l,
    const bf16* __restrict__ vTh, const bf16* __restrict__ vTl,
    float* __restrict__ rowt,
    float* __restrict__ num, float* __restrict__ denp)
{
  __shared__ bf16 Ph[32*64], Pl[32*64];
  __shared__ float cts[512];
  __shared__ float rtl[32];
  int lane = threadIdx.x & 63, w = threadIdx.x >> 6;
  int x = blockIdx.x;
  int tb = x >> 1, half = x & 1;
  int bh = blockIdx.y, b = bh >> 3, h = bh & 7;
  int t0 = tb*32;

  // ---- wave 0: gate scan (fp64 prefix-sum of f, prefix-max of i-A) ----
  if (w == 0){
    double fv[8]; float iv[8];
    for (int j=0;j<8;j++){
      int t = lane*8 + j;
      size_t ro = (size_t)(t*4+b)*N2;
      fv[j] = (double)(bfbits2f(*(const short*)(c2h+ro+1544+h)) +
                       bfbits2f(*(const short*)(c2l+ro+1544+h)));
      iv[j] = bfbits2f(*(const short*)(c2h+ro+1536+h)) +
              bfbits2f(*(const short*)(c2l+ro+1536+h));
    }
    double ps[8]; double s = 0.0;
    for (int j=0;j<8;j++){ s += fv[j]; ps[j] = s; }
    double run = s;
    for (int o=1;o<64;o<<=1){
      double u = __shfl_up(run, o);
      if (lane >= o) run += u;
    }
    double excl = run - s;
    float ct[8];
    for (int j=0;j<8;j++){
      ct[j] = (float)((double)iv[j] - (excl + ps[j]));
      cts[lane*8+j] = ct[j];
    }
    float pm[8]; float mm = -3.0e38f;
    for (int j=0;j<8;j++){ mm = fmaxf(mm, ct[j]); pm[j] = mm; }
    float incl = mm;
    for (int o=1;o<64;o<<=1){
      float u = __shfl_up(incl, o);
      if (lane >= o) incl = fmaxf(incl, u);
    }
    float ex = __shfl_up(incl, 1);
    if (lane == 0) ex = -3.0e38f;
    for (int j=0;j<8;j++){
      int t = lane*8 + j;
      float rt_ = -fmaxf(0.f, fmaxf(ex, pm[j]));   // = A_t - m_t (<= 0)
      if (t >= t0 && t < t0+32){
        rtl[t - t0] = rt_;
        if (half == 0) rowt[bh*512 + t] = rt_;     // owner writes for h_kernel
      }
    }
  }
  __syncthreads();

  int r = lane & 15, g = lane >> 4;
  int rq = g*4;

  short8 qh[2][2], ql[2][2];
  for (int mi=0;mi<2;mi++) for (int k0=0;k0<2;k0++){
    size_t off = (size_t)((t0+mi*16+r)*4+b)*N2 + h*64 + k0*32 + g*8;
    qh[mi][k0] = *(const short8*)(c2h+off);
    ql[mi][k0] = *(const short8*)(c2l+off);
  }
  float rtv[2][4];
  for (int mi=0;mi<2;mi++) for (int j=0;j<4;j++) rtv[mi][j] = rtl[mi*16+rq+j];

  f32x4 accPV[2];
  for (int i=0;i<2;i++) accPV[i] = (f32x4){0.f,0.f,0.f,0.f};
  float rsum[2][4];
  for (int i=0;i<2;i++) for (int j=0;j<4;j++) rsum[i][j] = 0.f;

  int nsb = (tb >> 1) + 1;
  for (int sb=half; sb<nsb; sb+=2){
    int s0 = sb*64;
    f32x4 acc[2];
    for (int i=0;i<2;i++) acc[i] = (f32x4){0.f,0.f,0.f,0.f};
    short8 kh[2], kl[2];
    for (int k0=0;k0<2;k0++){
      size_t off = (size_t)((s0+w*16+r)*4+b)*N2 + 512 + h*64 + k0*32 + g*8;
      kh[k0] = *(const short8*)(c2h+off);
      kl[k0] = *(const short8*)(c2l+off);
    }
    for (int k0=0;k0<2;k0++){
      for (int mi=0;mi<2;mi++) acc[mi] = MFMA(qh[mi][k0], kh[k0], acc[mi],0,0,0);
      for (int mi=0;mi<2;mi++) acc[mi] = MFMA(ql[mi][k0], kh[k0], acc[mi],0,0,0);
      for (int mi=0;mi<2;mi++) acc[mi] = MFMA(qh[mi][k0], kl[k0], acc[mi],0,0,0);
    }
    int sl = w*16 + r;
    int s = s0 + sl;
    float ctv = cts[s];
    for (int mi=0;mi<2;mi++){
      for (int j=0;j<4;j++){
        int tloc = mi*16 + rq + j;
        int t = t0 + tloc;
        float wg = (s <= t) ? __expf(rtv[mi][j] + ctv) : 0.f;
        float gv = acc[mi][j] * wg;
        rsum[mi][j] += gv;
        int col = ((((sl>>3) ^ (tloc&7))<<3) | (sl&7));
        split_bf(gv, Ph[tloc*64+col], Pl[tloc*64+col]);
      }
    }
    __syncthreads();
    short8 vh[2], vl[2];
    for (int k0=0;k0<2;k0++){
      size_t off = ((size_t)bh*64 + w*16 + r)*512 + s0 + k0*32 + g*8;
      vh[k0] = *(const short8*)(vTh+off);
      vl[k0] = *(const short8*)(vTl+off);
    }
    for (int k0=0;k0<2;k0++){
      short8 ph[2], pl[2];
      for (int mi=0;mi<2;mi++){
        int tloc = mi*16 + r;
        int slot = (k0*4 + g) ^ (tloc&7);
        ph[mi] = *(const short8*)(&Ph[tloc*64 + slot*8]);
        pl[mi] = *(const short8*)(&Pl[tloc*64 + slot*8]);
      }
      for (int mi=0;mi<2;mi++) accPV[mi] = MFMA(ph[mi], vh[k0], accPV[mi],0,0,0);
      for (int mi=0;mi<2;mi++) accPV[mi] = MFMA(pl[mi], vh[k0], accPV[mi],0,0,0);
      for (int mi=0;mi<2;mi++) accPV[mi] = MFMA(ph[mi], vl[k0], accPV[mi],0,0,0);
    }
    __syncthreads();
  }

  float* nump = num + (size_t)half*NUMSZ;
  for (int mi=0;mi<2;mi++)
    for (int j=0;j<4;j++){
      int t = t0 + mi*16 + rq + j;
      nump[((size_t)bh*512 + t)*64 + w*16 + r] = accPV[mi][j];
    }
  for (int mi=0;mi<2;mi++)
    for (int j=0;j<4;j++){
      float v = rsum[mi][j];
      v += __shfl_xor(v,1); v += __shfl_xor(v,2);
      v += __shfl_xor(v,4); v += __shfl_xor(v,8);
      if (r == 0){
        int t = t0 + mi*16 + rq + j;
        denp[((size_t)bh*512 + t)*8 + half*4 + w] = v;
      }
    }
}

// ===================== h = o*num/den, GroupNorm, +skip, *silu(r) -> hi/lo bf16 =====================
__global__ __launch_bounds__(512) void h_kernel(
    const float* __restrict__ num, const float* __restrict__ denp,
    const float* __restrict__ rowt,
    const bf16* __restrict__ c2h, const bf16* __restrict__ c2l,
    const bf16* __restrict__ c3h, const bf16* __restrict__ c3l,
    const bf16* __restrict__ c1h, const bf16* __restrict__ c1l,
    const float* __restrict__ gng, const float* __restrict__ gnb,
    bf16* __restrict__ oph, bf16* __restrict__ opl)
{
  int row = blockIdx.x, t = row >> 2, b = row & 3;
  int h = threadIdx.x >> 6, d = threadIdx.x & 63;
  int bh = b*8 + h;
  size_t bt = (size_t)bh*512 + t;
  size_t qo = (size_t)row*N2 + h*64 + d;
  float qs = bfbits2f(*(const short*)(c2h+qo)) + bfbits2f(*(const short*)(c2l+qo));
  for (int m=1; m<64; m<<=1) qs += __shfl_xor(qs, m);
  float dn = __expf(rowt[bt]) * qs;
  for (int p=0; p<8; p++) dn += denp[bt*8 + p];
  dn = fmaxf(fabsf(dn), 1.f);
  float nv = num[bt*64 + d] + num[NUMSZ + bt*64 + d];
  size_t io = (size_t)row*N3 + 512 + h*64 + d;
  float ov = bfbits2f(*(const short*)(c3h+io)) + bfbits2f(*(const short*)(c3l+io));
  float o = 1.f/(1.f + __expf(-ov));
  float hv = o * nv / dn;
  float s = hv, ss = hv*hv;
  for (int m=1; m<64; m<<=1){ s += __shfl_xor(s,m); ss += __shfl_xor(ss,m); }
  float mu = s*(1.f/64.f), var = ss*(1.f/64.f) - mu*mu;
  float gn = (hv - mu)*rsqrtf(var + EPSV)*gng[h*64+d] + gnb[h*64+d];
  size_t ks = (size_t)row*N2 + 1024 + h*64 + d;
  float sk = bfbits2f(*(const short*)(c2h+ks)) + bfbits2f(*(const short*)(c2l+ks));
  size_t kr = (size_t)row*N1 + 1024 + h*64 + d;
  float rv = bfbits2f(*(const short*)(c1h+kr)) + bfbits2f(*(const short*)(c1l+kr));
  float y = (gn + sk) * (rv/(1.f + __expf(-rv)));
  size_t oo = (size_t)row*512 + h*64 + d;
  split_bf(y, oph[oo], opl[oo]);
}

// ===================== host =====================
extern "C" void kernel_launch(void* const* d_in, const int* in_sizes, int n_in,
                              void* d_out, int out_size, void* d_ws, size_t ws_size,
                              hipStream_t stream)
{
  (void)in_sizes; (void)n_in; (void)out_size; (void)ws_size;
  const float* seq    = (const float*)d_in[0];
  const float* ln_g   = (const float*)d_in[1];
  const float* ln_b   = (const float*)d_in[2];
  const float* upl_w  = (const float*)d_in[3];
  const float* upl_b  = (const float*)d_in[4];
  const float* upr_w  = (const float*)d_in[5];
  const float* upr_b  = (const float*)d_in[6];
  const float* conv_w = (const float*)d_in[7];
  const float* conv_b = (const float*)d_in[8];
  const float* wq_w   = (const float*)d_in[9];
  const float* wq_b   = (const float*)d_in[10];
  const float* wk_w   = (const float*)d_in[11];
  const float* wk_b   = (const float*)d_in[12];
  const float* wv_w   = (const float*)d_in[13];
  const float* wv_b   = (const float*)d_in[14];
  const float* wo_w   = (const float*)d_in[15];
  const float* wo_b   = (const float*)d_in[16];
  const float* wi_w   = (const float*)d_in[17];
  const float* wi_b   = (const float*)d_in[18];
  const float* wf_w   = (const float*)d_in[19];
  const float* wf_b   = (const float*)d_in[20];
  const float* skip_w = (const float*)d_in[21];
  const float* gn_g   = (const float*)d_in[22];
  const float* gn_b   = (const float*)d_in[23];
  const float* down_w = (const float*)d_in[24];
  const float* down_b = (const float*)d_in[25];

  char* ws = (char*)d_ws;
  size_t off = 0;
  auto alloc = [&](size_t bytes)->char*{
    char* p = ws + off; off = (off + bytes + 255) & ~(size_t)255; return p;
  };
  bf16*  W1h = (bf16*)alloc((size_t)3*N1*512*2);
  bf16*  W1l = (bf16*)alloc((size_t)3*N1*512*2);
  bf16*  W2h = (bf16*)alloc((size_t)3*N2*1024*2);
  bf16*  W2l = (bf16*)alloc((size_t)3*N2*1024*2);
  bf16*  W3h = (bf16*)alloc((size_t)3*N3*1024*2);
  bf16*  W3l = (bf16*)alloc((size_t)3*N3*1024*2);
  bf16*  W4h = (bf16*)alloc((size_t)3*512*512*2);
  bf16*  W4l = (bf16*)alloc((size_t)3*512*512*2);
  float* b1  = (float*)alloc((size_t)3*N1*4);
  float* b2  = (float*)alloc((size_t)3*N2*4);
  float* b3  = (float*)alloc((size_t)3*N3*4);
  float* b4  = (float*)alloc((size_t)3*512*4);
  bf16*  xnh = (bf16*)alloc((size_t)NROW*512*2);
  bf16*  xnl = (bf16*)alloc((size_t)NROW*512*2);
  bf16*  c1h = (bf16*)alloc((size_t)NROW*N1*2);
  bf16*  c1l = (bf16*)alloc((size_t)NROW*N1*2);
  bf16*  xch = (bf16*)alloc((size_t)NROW*1024*2);
  bf16*  xcl = (bf16*)alloc((size_t)NROW*1024*2);
  bf16*  c2h = (bf16*)alloc((size_t)NROW*N2*2);
  bf16*  c2l = (bf16*)alloc((size_t)NROW*N2*2);
  bf16*  c3h = (bf16*)alloc((size_t)NROW*N3*2);
  bf16*  c3l = (bf16*)alloc((size_t)NROW*N3*2);
  bf16*  vTh = (bf16*)alloc((size_t)32*64*512*2);
  bf16*  vTl = (bf16*)alloc((size_t)32*64*512*2);
  float* rowt= (float*)alloc((size_t)32*512*4);
  float* denp= (float*)alloc((size_t)32*512*8*4);
  float* num = (float*)alloc((size_t)2*NUMSZ*4);
  bf16*  oph = (bf16*)alloc((size_t)NROW*512*2);
  bf16*  opl = (bf16*)alloc((size_t)NROW*512*2);
  float* xA  = (float*)alloc((size_t)NROW*512*4);
  float* xB  = (float*)alloc((size_t)NROW*512*4);

  // --- pack all weights/biases to hi/lo bf16 (k-scale folded) in ONE dispatch ---
  pack_all<<<dim3(3713,3), 256, 0, stream>>>(
      upl_w, upr_w, wq_w, wk_w, skip_w, wi_w, wf_w, wv_w, wo_w, down_w,
      upl_b, upr_b, wq_b, wk_b, wi_b, wf_b, wv_b, wo_b, down_b,
      W1h, W1l, W2h, W2l, W3h, W3l, W4h, W4l, b1, b2, b3, b4);

  for (int l = 0; l < 3; l++){
    const float* x_in = (l == 0) ? seq : ((l == 1) ? xA : xB);
    float* x_out = (l == 0) ? xA : ((l == 1) ? xB : (float*)d_out);

    ln_kernel<<<NROW, 256, 0, stream>>>(x_in, ln_g + l*512, ln_b + l*512, xnh, xnl);
    gemm_s64<<<32*12, 256, 0, stream>>>(
        xnh, xnl, W1h + (size_t)l*N1*512, W1l + (size_t)l*N1*512,
        b1 + l*N1, nullptr, c1h, c1l, nullptr, N1, 512, 512, 12);
    conv_kernel<<<NROW, 256, 0, stream>>>(c1h, c1l, conv_w + l*4, conv_b + l,
                                          xch, xcl);
    gemm23<<<21*16, 512, 0, stream>>>(
        xch, xcl, W2h + (size_t)l*N2*1024, W2l + (size_t)l*N2*1024, b2 + l*N2,
        c2h, c2l,
        c1h, c1l, W3h + (size_t)l*N3*1024, W3l + (size_t)l*N3*1024, b3 + l*N3,
        c3h, c3l);
    vtrans_kernel<<<dim3(8,32), 512, 0, stream>>>(c3h, c3l, vTh, vTl);
    attn_kernel<<<dim3(32,32), 256, 0, stream>>>(c2h, c2l, vTh, vTl,
                                                 rowt, num, denp);
    h_kernel<<<NROW, 512, 0, stream>>>(num, denp, rowt, c2h, c2l, c3h, c3l,
                                       c1h, c1l, gn_g + l*512, gn_b + l*512,
                                       oph, opl);
    gemm_s64<<<32*4, 256, 0, stream>>>(
        oph, opl, W4h + (size_t)l*512*512, W4l + (size_t)l*512*512,
        b4 + l*512, x_out, nullptr, nullptr, x_in, 512, 512, 512, 4);
  }
}

// Round 12
// 387.723 us; speedup vs baseline: 1.1116x; 1.1116x over previous
//
#include <hip/hip_runtime.h>
#include <hip/hip_bf16.h>
#include <cstdint>
#include <cstddef>

typedef short short8 __attribute__((ext_vector_type(8)));
typedef short short4v __attribute__((ext_vector_type(4)));
typedef float f32x4 __attribute__((ext_vector_type(4)));
typedef __hip_bfloat16 bf16;

#define NROW 2048      // S*B rows
#define N1 1536        // [upl(1024); upr(512)]
#define N2 1664        // [wq(512); wk(512); skip(512); wi(8); wf(8); pad(112)]
#define N3 1024        // [wv(512); wo(512)]
#define EPSV 1e-5f

static __device__ __forceinline__ bf16 f2bf(float v){ return __float2bfloat16(v); }
static __device__ __forceinline__ float bfbits2f(short s){
  unsigned u = ((unsigned)(unsigned short)s) << 16;
  float f; __builtin_memcpy(&f, &u, 4); return f;
}
static __device__ __forceinline__ void split_bf(float v, bf16& h, bf16& l){
  h = __float2bfloat16(v);
  l = __float2bfloat16(v - __bfloat162float(h));
}

static __device__ __forceinline__ void gload16(const bf16* g, bf16* l){
  __builtin_amdgcn_global_load_lds(
      (const __attribute__((address_space(1))) void*)(g),
      (__attribute__((address_space(3))) void*)(l), 16, 0, 0);
}

#define MFMA __builtin_amdgcn_mfma_f32_16x16x32_bf16

// ===================== single mega weight/bias pack kernel (vectorized) =====================
// W1: 768 blocks (2 rows each) | W2: 1664 | W3: 1024 | W4: 256 (2 rows) | bias: 1
__global__ __launch_bounds__(256) void pack_all(
    const float* __restrict__ upl, const float* __restrict__ upr,
    const float* __restrict__ wq,  const float* __restrict__ wk,
    const float* __restrict__ skp, const float* __restrict__ wi,
    const float* __restrict__ wf,  const float* __restrict__ wv,
    const float* __restrict__ wo,  const float* __restrict__ dw,
    const float* __restrict__ uplb, const float* __restrict__ uprb,
    const float* __restrict__ wqb,  const float* __restrict__ wkb,
    const float* __restrict__ wib,  const float* __restrict__ wfb,
    const float* __restrict__ wvb,  const float* __restrict__ wob,
    const float* __restrict__ dwb,
    bf16* __restrict__ W1h, bf16* __restrict__ W1l,
    bf16* __restrict__ W2h, bf16* __restrict__ W2l,
    bf16* __restrict__ W3h, bf16* __restrict__ W3l,
    bf16* __restrict__ W4h, bf16* __restrict__ W4l,
    float* __restrict__ b1, float* __restrict__ b2,
    float* __restrict__ b3, float* __restrict__ b4)
{
  int l = blockIdx.y;
  int bx = blockIdx.x;
  if (bx < 768){                        // ---- W1: [upl(1024); upr(512)], K=512, 2 rows/block
    int r = bx*2 + (threadIdx.x >> 7);
    int c4 = threadIdx.x & 127;
    const float* src = (r < 1024) ? upl + ((size_t)l*1024 + r)*512
                                  : upr + ((size_t)l*512 + (r-1024))*512;
    size_t o = ((size_t)l*N1 + r)*512 + c4*4;
    f32x4 v = *(const f32x4*)(src + c4*4);
    short4v hh, ll;
    for (int e=0;e<4;e++){ bf16 h_,l_; split_bf(v[e],h_,l_);
      hh[e] = *(short*)&h_; ll[e] = *(short*)&l_; }
    *(short4v*)(W1h+o) = hh; *(short4v*)(W1l+o) = ll;
  } else if (bx < 2432){                // ---- W2, K=1024
    int r = bx - 768;
    int c4 = threadIdx.x;
    const float* src; float sc = 1.f;
    if (r < 512)        src = wq  + ((size_t)l*512 + r)*1024;
    else if (r < 1024){ src = wk  + ((size_t)l*512 + r-512)*1024; sc = 0.125f; }
    else if (r < 1536)  src = skp + ((size_t)l*512 + r-1024)*1024;
    else if (r < 1544)  src = wi  + ((size_t)l*8   + r-1536)*1024;
    else if (r < 1552)  src = wf  + ((size_t)l*8   + r-1544)*1024;
    else src = nullptr;
    size_t o = ((size_t)l*N2 + r)*1024 + c4*4;
    f32x4 v = src ? *(const f32x4*)(src + c4*4) : (f32x4){0.f,0.f,0.f,0.f};
    short4v hh, ll;
    for (int e=0;e<4;e++){ bf16 h_,l_; split_bf(v[e]*sc,h_,l_);
      hh[e] = *(short*)&h_; ll[e] = *(short*)&l_; }
    *(short4v*)(W2h+o) = hh; *(short4v*)(W2l+o) = ll;
  } else if (bx < 3456){                // ---- W3: [wv; wo], K=1024
    int r = bx - 2432;
    int c4 = threadIdx.x;
    const float* src = (r < 512) ? wv + ((size_t)l*512 + r)*1024
                                 : wo + ((size_t)l*512 + (r-512))*1024;
    size_t o = ((size_t)l*N3 + r)*1024 + c4*4;
    f32x4 v = *(const f32x4*)(src + c4*4);
    short4v hh, ll;
    for (int e=0;e<4;e++){ bf16 h_,l_; split_bf(v[e],h_,l_);
      hh[e] = *(short*)&h_; ll[e] = *(short*)&l_; }
    *(short4v*)(W3h+o) = hh; *(short4v*)(W3l+o) = ll;
  } else if (bx < 3712){                // ---- W4 (down), K=512, 2 rows/block
    int r = (bx - 3456)*2 + (threadIdx.x >> 7);
    int c4 = threadIdx.x & 127;
    const float* src = dw + ((size_t)l*512 + r)*512;
    size_t o = ((size_t)l*512 + r)*512 + c4*4;
    f32x4 v = *(const f32x4*)(src + c4*4);
    short4v hh, ll;
    for (int e=0;e<4;e++){ bf16 h_,l_; split_bf(v[e],h_,l_);
      hh[e] = *(short*)&h_; ll[e] = *(short*)&l_; }
    *(short4v*)(W4h+o) = hh; *(short4v*)(W4l+o) = ll;
  } else {                              // ---- biases
    for (int j = threadIdx.x; j < N1; j += 256)
      b1[l*N1+j] = (j < 1024) ? uplb[l*1024+j] : uprb[l*512+j-1024];
    for (int j = threadIdx.x; j < N2; j += 256){
      float v = 0.f;
      if (j < 512)        v = wqb[l*512+j];
      else if (j < 1024)  v = wkb[l*512+j-512]*0.125f;
      else if (j < 1536)  v = 0.f;
      else if (j < 1544)  v = wib[l*8+j-1536];
      else if (j < 1552)  v = wfb[l*8+j-1544];
      b2[l*N2+j] = v;
    }
    for (int j = threadIdx.x; j < N3; j += 256)
      b3[l*N3+j] = (j < 512) ? wvb[l*512+j] : wob[l*512+j-512];
    for (int j = threadIdx.x; j < 512; j += 256)
      b4[l*512+j] = dwb[l*512+j];
  }
}

// ===================== LDS-staged split-bf16 GEMM core (128x128, 8 waves) =====================
static __device__ __forceinline__ void gemm_core(
    bf16* __restrict__ sm,        // 2 bufs x [Ah|Al|Bh|Bl] x 4096 bf16
    int bx, int by,
    const bf16* __restrict__ Ah, const bf16* __restrict__ Al,
    const bf16* __restrict__ Wh, const bf16* __restrict__ Wl,
    const float* __restrict__ bias, float* __restrict__ Cf,
    bf16* __restrict__ Cbh, bf16* __restrict__ Cbl,
    const float* __restrict__ resid, int N, int K, int lda)
{
  int tid = threadIdx.x;
  int lane = tid & 63, w = tid >> 6;
  int wr = w >> 2, wc = w & 3;            // 2 x 4 waves, each 64(M) x 32(N)
  int m0 = by*128, n0 = bx*128;
  int srow = tid >> 2, sslot = tid & 3;   // coalesced: 4 lanes per 64B row
  int gcol = ((sslot ^ (srow & 3)) * 8);  // pre-swizzled global slot
  const bf16* gAh = Ah + (size_t)(m0 + srow)*lda + gcol;
  const bf16* gAl = Al + (size_t)(m0 + srow)*lda + gcol;
  const bf16* gBh = Wh + (size_t)(n0 + srow)*K + gcol;
  const bf16* gBl = Wl + (size_t)(n0 + srow)*K + gcol;

  f32x4 acc[4][2];
  for (int i=0;i<4;i++) for (int j=0;j<2;j++) acc[i][j] = (f32x4){0.f,0.f,0.f,0.f};

  int r = lane & 15, g = lane >> 4;
  int xs = (g ^ (r & 3)) * 8;             // swizzled read slot
  int aoff[4], boff[2];
  for (int mi=0;mi<4;mi++) aoff[mi] = (wr*64 + mi*16 + r)*32 + xs;
  for (int ni=0;ni<2;ni++) boff[ni] = (wc*32 + ni*16 + r)*32 + xs;

  int nt = K >> 5;
#define STAGE_T(base, kk) do{ bf16* _d = sm + (base) + tid*8; \
    gload16(gAh + (kk), _d); \
    gload16(gAl + (kk), _d + 4096); \
    gload16(gBh + (kk), _d + 8192); \
    gload16(gBl + (kk), _d + 12288); }while(0)

  STAGE_T(0, 0);
  asm volatile("s_waitcnt vmcnt(0)" ::: "memory");
  __builtin_amdgcn_s_barrier();

  for (int t = 0; t < nt; ++t){
    int cb = (t & 1) * 16384;
    if (t + 1 < nt) STAGE_T(16384 - cb, (t+1)*32);
    const bf16* sA = sm + cb;
    short8 ah[4], al[4], bh2[2], bl2[2];
    for (int mi=0;mi<4;mi++){
      ah[mi] = *(const short8*)(sA + aoff[mi]);
      al[mi] = *(const short8*)(sA + 4096 + aoff[mi]);
    }
    for (int ni=0;ni<2;ni++){
      bh2[ni] = *(const short8*)(sA + 8192 + boff[ni]);
      bl2[ni] = *(const short8*)(sA + 12288 + boff[ni]);
    }
    for (int mi=0;mi<4;mi++) for (int ni=0;ni<2;ni++)
      acc[mi][ni] = MFMA(ah[mi], bh2[ni], acc[mi][ni],0,0,0);
    for (int mi=0;mi<4;mi++) for (int ni=0;ni<2;ni++)
      acc[mi][ni] = MFMA(al[mi], bh2[ni], acc[mi][ni],0,0,0);
    for (int mi=0;mi<4;mi++) for (int ni=0;ni<2;ni++)
      acc[mi][ni] = MFMA(ah[mi], bl2[ni], acc[mi][ni],0,0,0);
    asm volatile("s_waitcnt vmcnt(0)" ::: "memory");
    __builtin_amdgcn_s_barrier();
  }
#undef STAGE_T

  for (int mi=0;mi<4;mi++) for (int ni=0;ni<2;ni++){
    int col = n0 + wc*32 + ni*16 + r;
    float bv = bias ? bias[col] : 0.f;
    for (int j=0;j<4;j++){
      int row = m0 + wr*64 + mi*16 + g*4 + j;
      float v = acc[mi][ni][j] + bv;
      size_t o = (size_t)row*N + col;
      if (resid) v += resid[o];
      if (Cf) Cf[o] = v;
      if (Cbh) split_bf(v, Cbh[o], Cbl[o]);
    }
  }
}

// ===================== 64x128-tile GEMM core (256 thr, 4 waves, 48KB LDS) =====================
static __device__ __forceinline__ void gemm_core64(
    bf16* __restrict__ sm,        // 2 bufs x [Ah(2048)|Al(2048)|Bh(4096)|Bl(4096)]
    int bx, int by,
    const bf16* __restrict__ Ah, const bf16* __restrict__ Al,
    const bf16* __restrict__ Wh, const bf16* __restrict__ Wl,
    const float* __restrict__ bias, float* __restrict__ Cf,
    bf16* __restrict__ Cbh, bf16* __restrict__ Cbl,
    const float* __restrict__ resid, int N, int K, int lda)
{
  int tid = threadIdx.x;                  // 256 threads, 4 waves
  int lane = tid & 63, w = tid >> 6;      // wave w covers cols w*32..+31
  int m0 = by*64, n0 = bx*128;
  int srow = tid >> 2, sslot = tid & 3;
  int gcol = ((sslot ^ (srow & 3)) * 8);
  const bf16* gAh = Ah + (size_t)(m0 + srow)*lda + gcol;
  const bf16* gAl = Al + (size_t)(m0 + srow)*lda + gcol;
  const bf16* gBh = Wh + (size_t)(n0 + srow)*K + gcol;
  const bf16* gBl = Wl + (size_t)(n0 + srow)*K + gcol;
  size_t pstr = (size_t)64*K;             // B rows 64..127

  f32x4 acc[4][2];
  for (int i=0;i<4;i++) for (int j=0;j<2;j++) acc[i][j] = (f32x4){0.f,0.f,0.f,0.f};

  int r = lane & 15, g = lane >> 4;
  int xs = (g ^ (r & 3)) * 8;
  int aoff[4], boff[2];
  for (int mi=0;mi<4;mi++) aoff[mi] = (mi*16 + r)*32 + xs;
  for (int ni=0;ni<2;ni++) boff[ni] = (w*32 + ni*16 + r)*32 + xs;

  int nt = K >> 5;
#define STAGE64(base, kk) do{ bf16* _d = sm + (base) + tid*8; \
    gload16(gAh + (kk), _d); \
    gload16(gAl + (kk), _d + 2048); \
    gload16(gBh + (kk), _d + 4096);  gload16(gBh + (kk) + pstr, _d + 6144); \
    gload16(gBl + (kk), _d + 8192);  gload16(gBl + (kk) + pstr, _d + 10240); }while(0)

  STAGE64(0, 0);
  asm volatile("s_waitcnt vmcnt(0)" ::: "memory");
  __builtin_amdgcn_s_barrier();

  for (int t = 0; t < nt; ++t){
    int cb = (t & 1) * 12288;
    if (t + 1 < nt) STAGE64(12288 - cb, (t+1)*32);
    const bf16* sA = sm + cb;
    short8 ah[4], al[4], bh2[2], bl2[2];
    for (int mi=0;mi<4;mi++){
      ah[mi] = *(const short8*)(sA + aoff[mi]);
      al[mi] = *(const short8*)(sA + 2048 + aoff[mi]);
    }
    for (int ni=0;ni<2;ni++){
      bh2[ni] = *(const short8*)(sA + 4096 + boff[ni]);
      bl2[ni] = *(const short8*)(sA + 8192 + boff[ni]);
    }
    for (int mi=0;mi<4;mi++) for (int ni=0;ni<2;ni++)
      acc[mi][ni] = MFMA(ah[mi], bh2[ni], acc[mi][ni],0,0,0);
    for (int mi=0;mi<4;mi++) for (int ni=0;ni<2;ni++)
      acc[mi][ni] = MFMA(al[mi], bh2[ni], acc[mi][ni],0,0,0);
    for (int mi=0;mi<4;mi++) for (int ni=0;ni<2;ni++)
      acc[mi][ni] = MFMA(ah[mi], bl2[ni], acc[mi][ni],0,0,0);
    asm volatile("s_waitcnt vmcnt(0)" ::: "memory");
    __builtin_amdgcn_s_barrier();
  }
#undef STAGE64

  for (int mi=0;mi<4;mi++) for (int ni=0;ni<2;ni++){
    int col = n0 + w*32 + ni*16 + r;
    float bv = bias ? bias[col] : 0.f;
    for (int j=0;j<4;j++){
      int row = m0 + mi*16 + g*4 + j;
      float v = acc[mi][ni][j] + bv;
      size_t o = (size_t)row*N + col;
      if (resid) v += resid[o];
      if (Cf) Cf[o] = v;
      if (Cbh) split_bf(v, Cbh[o], Cbl[o]);
    }
  }
}

// standalone small GEMM (64x128): 1D grid (divisible by 8), XCD swizzle
__global__ __launch_bounds__(256) void gemm_s64(
    const bf16* __restrict__ Ah, const bf16* __restrict__ Al,
    const bf16* __restrict__ Wh, const bf16* __restrict__ Wl,
    const float* __restrict__ bias, float* __restrict__ Cf,
    bf16* __restrict__ Cbh, bf16* __restrict__ Cbl,
    const float* __restrict__ resid, int N, int K, int lda, int nbx)
{
  __shared__ bf16 sm[2*12288];
  int id = blockIdx.x;
  int cpx = gridDim.x >> 3;
  int swz = (id & 7)*cpx + (id >> 3);
  int by = swz / nbx, bx = swz - by*nbx;
  gemm_core64(sm, bx, by, Ah, Al, Wh, Wl, bias, Cf, Cbh, Cbl, resid, N, K, lda);
}

// fused gemm2+gemm3 (both K=1024): bx<13 -> set2 (N2), else set3 (N3, A=c1 via lda)
__global__ __launch_bounds__(512) void gemm23(
    const bf16* __restrict__ A2h, const bf16* __restrict__ A2l,
    const bf16* __restrict__ W2h, const bf16* __restrict__ W2l,
    const float* __restrict__ b2,
    bf16* __restrict__ c2h, bf16* __restrict__ c2l,
    const bf16* __restrict__ A3h, const bf16* __restrict__ A3l,
    const bf16* __restrict__ W3h, const bf16* __restrict__ W3l,
    const float* __restrict__ b3,
    bf16* __restrict__ c3h, bf16* __restrict__ c3l)
{
  __shared__ bf16 sm[2*4*4096];
  int id = blockIdx.x;
  int cpx = gridDim.x >> 3;          // 336/8 = 42
  int swz = (id & 7)*cpx + (id >> 3);
  int by = swz / 21, bx = swz - by*21;
  if (bx < 13)
    gemm_core(sm, bx, by, A2h, A2l, W2h, W2l, b2, nullptr, c2h, c2l,
              nullptr, N2, 1024, 1024);
  else
    gemm_core(sm, bx-13, by, A3h, A3l, W3h, W3l, b3, nullptr, c3h, c3l,
              nullptr, N3, 1024, N1);
}

// ===================== LayerNorm (fp32 in -> hi/lo bf16 out) =====================
__global__ __launch_bounds__(256) void ln_kernel(const float* __restrict__ x,
    const float* __restrict__ g, const float* __restrict__ bt,
    bf16* __restrict__ xnh, bf16* __restrict__ xnl)
{
  int row = blockIdx.x, t = threadIdx.x;
  float v0 = x[(size_t)row*512 + t], v1 = x[(size_t)row*512 + 256 + t];
  float s = v0 + v1, ss = v0*v0 + v1*v1;
  for (int m=1; m<64; m<<=1){ s += __shfl_xor(s,m); ss += __shfl_xor(ss,m); }
  __shared__ float sh[8];
  int w = t >> 6, lane = t & 63;
  if (lane == 0){ sh[w] = s; sh[4+w] = ss; }
  __syncthreads();
  s = sh[0]+sh[1]+sh[2]+sh[3]; ss = sh[4]+sh[5]+sh[6]+sh[7];
  float mu = s*(1.f/512.f), var = ss*(1.f/512.f) - mu*mu;
  float rs = rsqrtf(var + EPSV);
  float y0 = (v0-mu)*rs*g[t]     + bt[t];
  float y1 = (v1-mu)*rs*g[256+t] + bt[256+t];
  split_bf(y0, xnh[(size_t)row*512 + t],       xnl[(size_t)row*512 + t]);
  split_bf(y1, xnh[(size_t)row*512 + 256 + t], xnl[(size_t)row*512 + 256 + t]);
}

// ===================== causal conv + silu; reads c1 hi/lo, writes x_c hi/lo only =====================
__global__ __launch_bounds__(256) void conv_kernel(
    const bf16* __restrict__ c1h, const bf16* __restrict__ c1l,
    const float* __restrict__ cw, const float* __restrict__ cb,
    bf16* __restrict__ xch, bf16* __restrict__ xcl)
{
  int row = blockIdx.x;
  size_t rb = (size_t)row*N1;
  float w0=cw[0], w1=cw[1], w2=cw[2], w3=cw[3], bb=cb[0];
  int j0 = threadIdx.x*4;          // 0..1023, 4 consecutive outputs
  float x[7];
  for (int k=0;k<3;k++){
    int j = j0-3+k;
    x[k] = (j>=0) ? (bfbits2f(*(const short*)(c1h+rb+j)) +
                     bfbits2f(*(const short*)(c1l+rb+j))) : 0.f;
  }
  short4v h4 = *(const short4v*)(c1h+rb+j0);
  short4v l4 = *(const short4v*)(c1l+rb+j0);
  for (int k=0;k<4;k++) x[3+k] = bfbits2f(h4[k]) + bfbits2f(l4[k]);
  for (int i=0;i<4;i++){
    float y = bb + w0*x[i] + w1*x[i+1] + w2*x[i+2] + w3*x[i+3];
    float sg = 1.f/(1.f + __expf(-y));
    size_t o = (size_t)row*1024 + j0 + i;
    split_bf(y*sg, xch[o], xcl[o]);
  }
}

// ===================== prep: LDS-transposed vtrans (bx<8) + gate scan (bx==8) =====================
__global__ __launch_bounds__(512) void prep_kernel(
    const bf16* __restrict__ c3h, const bf16* __restrict__ c3l,
    const bf16* __restrict__ c2h, const bf16* __restrict__ c2l,
    bf16* __restrict__ vTh, bf16* __restrict__ vTl,
    float* __restrict__ rowt, float* __restrict__ colt)
{
  int bh = blockIdx.y, b = bh >> 3, h = bh & 7;
  if (blockIdx.x < 8){
    // ---- vtrans tile: s in [s0, s0+64), all 64 d; coalesced both sides via LDS
    __shared__ short th[64*66], tl[64*66];
    int s0 = blockIdx.x*64;
    int sl = threadIdx.x >> 3, d8 = (threadIdx.x & 7)*8;
    size_t i = (size_t)((s0+sl)*4+b)*N3 + h*64 + d8;
    short8 hv = *(const short8*)(c3h+i);
    short8 lv = *(const short8*)(c3l+i);
    for (int e=0;e<8;e++){
      th[sl*66 + d8+e] = hv[e];
      tl[sl*66 + d8+e] = lv[e];
    }
    __syncthreads();
    int dl = threadIdx.x >> 3, s8 = (threadIdx.x & 7)*8;
    short8 oh, ol;
    for (int e=0;e<8;e++){
      oh[e] = th[(s8+e)*66 + dl];
      ol[e] = tl[(s8+e)*66 + dl];
    }
    size_t o = ((size_t)bh*64 + dl)*512 + s0 + s8;
    *(short8*)(vTh+o) = oh;
    *(short8*)(vTl+o) = ol;
    return;
  }
  // ---- barrier-free per-wave scan (fp64 sum, fp32 max), first wave only
  if (threadIdx.x >= 64) return;
  int lane = threadIdx.x;
  double fv[8]; float iv[8];
  for (int j=0;j<8;j++){
    int t = lane*8 + j;
    size_t ro = (size_t)(t*4+b)*N2;
    fv[j] = (double)(bfbits2f(*(const short*)(c2h+ro+1544+h)) +
                     bfbits2f(*(const short*)(c2l+ro+1544+h)));
    iv[j] = bfbits2f(*(const short*)(c2h+ro+1536+h)) +
            bfbits2f(*(const short*)(c2l+ro+1536+h));
  }
  double ps[8]; double s = 0.0;
  for (int j=0;j<8;j++){ s += fv[j]; ps[j] = s; }
  double run = s;
  for (int o=1;o<64;o<<=1){
    double u = __shfl_up(run, o);
    if (lane >= o) run += u;
  }
  double excl = run - s;
  float ct[8];
  for (int j=0;j<8;j++){
    ct[j] = (float)((double)iv[j] - (excl + ps[j]));
    colt[bh*512 + lane*8 + j] = ct[j];
  }
  float pm[8]; float mm = -3.0e38f;
  for (int j=0;j<8;j++){ mm = fmaxf(mm, ct[j]); pm[j] = mm; }
  float incl = mm;
  for (int o=1;o<64;o<<=1){
    float u = __shfl_up(incl, o);
    if (lane >= o) incl = fmaxf(incl, u);
  }
  float ex = __shfl_up(incl, 1);
  if (lane == 0) ex = -3.0e38f;
  for (int j=0;j<8;j++){
    float inc = fmaxf(ex, pm[j]);
    rowt[bh*512 + lane*8 + j] = -fmaxf(0.f, inc);   // = A_t - m_t (<= 0)
  }
}

// ===================== fused attention: QK^T -> decay/mask -> PV + den =====================
// grid (16, 32 bh) with balanced tb pairing; 256 thr (4 waves).
__global__ __launch_bounds__(256) void attn_kernel(
    const bf16* __restrict__ c2h, const bf16* __restrict__ c2l,
    const bf16* __restrict__ vTh, const bf16* __restrict__ vTl,
    const float* __restrict__ rowt, const float* __restrict__ colt,
    float* __restrict__ num, float* __restrict__ denp)
{
  __shared__ bf16 Ph[32*64], Pl[32*64];
  __shared__ float cts[512];
  int lane = threadIdx.x & 63, w = threadIdx.x >> 6;
  int x = blockIdx.x;
  int tb = (x & 1) ? (15 - (x >> 1)) : (x >> 1);   // balanced pairs (sum const)
  int bh = blockIdx.y, b = bh >> 3, h = bh & 7;
  int t0 = tb*32;

  // load colterm into LDS (coalesced)
  cts[threadIdx.x]       = colt[bh*512 + threadIdx.x];
  cts[256 + threadIdx.x] = colt[bh*512 + 256 + threadIdx.x];
  __syncthreads();

  int r = lane & 15, g = lane >> 4;
  int rq = g*4;

  short8 qh[2][2], ql[2][2];
  for (int mi=0;mi<2;mi++) for (int k0=0;k0<2;k0++){
    size_t off = (size_t)((t0+mi*16+r)*4+b)*N2 + h*64 + k0*32 + g*8;
    qh[mi][k0] = *(const short8*)(c2h+off);
    ql[mi][k0] = *(const short8*)(c2l+off);
  }
  float rtv[2][4];
  for (int mi=0;mi<2;mi++) for (int j=0;j<4;j++)
    rtv[mi][j] = rowt[bh*512 + t0 + mi*16 + rq + j];

  f32x4 accPV[2];
  for (int i=0;i<2;i++) accPV[i] = (f32x4){0.f,0.f,0.f,0.f};
  float rsum[2][4];
  for (int i=0;i<2;i++) for (int j=0;j<4;j++) rsum[i][j] = 0.f;

  int nsb = (tb >> 1) + 1;
  for (int sb=0; sb<nsb; ++sb){
    int s0 = sb*64;
    f32x4 acc[2];
    for (int i=0;i<2;i++) acc[i] = (f32x4){0.f,0.f,0.f,0.f};
    short8 kh[2], kl[2];
    for (int k0=0;k0<2;k0++){
      size_t off = (size_t)((s0+w*16+r)*4+b)*N2 + 512 + h*64 + k0*32 + g*8;
      kh[k0] = *(const short8*)(c2h+off);
      kl[k0] = *(const short8*)(c2l+off);
    }
    for (int k0=0;k0<2;k0++){
      for (int mi=0;mi<2;mi++) acc[mi] = MFMA(qh[mi][k0], kh[k0], acc[mi],0,0,0);
      for (int mi=0;mi<2;mi++) acc[mi] = MFMA(ql[mi][k0], kh[k0], acc[mi],0,0,0);
      for (int mi=0;mi<2;mi++) acc[mi] = MFMA(qh[mi][k0], kl[k0], acc[mi],0,0,0);
    }
    int sl = w*16 + r;
    int s = s0 + sl;
    float ctv = cts[s];
    for (int mi=0;mi<2;mi++){
      for (int j=0;j<4;j++){
        int tloc = mi*16 + rq + j;
        int t = t0 + tloc;
        float wg = (s <= t) ? __expf(rtv[mi][j] + ctv) : 0.f;
        float gv = acc[mi][j] * wg;
        rsum[mi][j] += gv;
        int col = ((((sl>>3) ^ (tloc&7))<<3) | (sl&7));
        split_bf(gv, Ph[tloc*64+col], Pl[tloc*64+col]);
      }
    }
    __syncthreads();
    short8 vh[2], vl[2];
    for (int k0=0;k0<2;k0++){
      size_t off = ((size_t)bh*64 + w*16 + r)*512 + s0 + k0*32 + g*8;
      vh[k0] = *(const short8*)(vTh+off);
      vl[k0] = *(const short8*)(vTl+off);
    }
    for (int k0=0;k0<2;k0++){
      short8 ph[2], pl[2];
      for (int mi=0;mi<2;mi++){
        int tloc = mi*16 + r;
        int slot = (k0*4 + g) ^ (tloc&7);
        ph[mi] = *(const short8*)(&Ph[tloc*64 + slot*8]);
        pl[mi] = *(const short8*)(&Pl[tloc*64 + slot*8]);
      }
      for (int mi=0;mi<2;mi++) accPV[mi] = MFMA(ph[mi], vh[k0], accPV[mi],0,0,0);
      for (int mi=0;mi<2;mi++) accPV[mi] = MFMA(pl[mi], vh[k0], accPV[mi],0,0,0);
      for (int mi=0;mi<2;mi++) accPV[mi] = MFMA(ph[mi], vl[k0], accPV[mi],0,0,0);
    }
    __syncthreads();
  }

  for (int mi=0;mi<2;mi++)
    for (int j=0;j<4;j++){
      int t = t0 + mi*16 + rq + j;
      num[((size_t)bh*512 + t)*64 + w*16 + r] = accPV[mi][j];
    }
  for (int mi=0;mi<2;mi++)
    for (int j=0;j<4;j++){
      float v = rsum[mi][j];
      v += __shfl_xor(v,1); v += __shfl_xor(v,2);
      v += __shfl_xor(v,4); v += __shfl_xor(v,8);
      if (r == 0){
        int t = t0 + mi*16 + rq + j;
        denp[((size_t)bh*512 + t)*4 + w] = v;
      }
    }
}

// ===================== h = o*num/den, GroupNorm, +skip, *silu(r) -> hi/lo bf16 =====================
__global__ __launch_bounds__(512) void h_kernel(
    const float* __restrict__ num, const float* __restrict__ denp,
    const float* __restrict__ rowt,
    const bf16* __restrict__ c2h, const bf16* __restrict__ c2l,
    const bf16* __restrict__ c3h, const bf16* __restrict__ c3l,
    const bf16* __restrict__ c1h, const bf16* __restrict__ c1l,
    const float* __restrict__ gng, const float* __restrict__ gnb,
    bf16* __restrict__ oph, bf16* __restrict__ opl)
{
  int row = blockIdx.x, t = row >> 2, b = row & 3;
  int h = threadIdx.x >> 6, d = threadIdx.x & 63;
  int bh = b*8 + h;
  size_t bt = (size_t)bh*512 + t;
  size_t qo = (size_t)row*N2 + h*64 + d;
  float qs = bfbits2f(*(const short*)(c2h+qo)) + bfbits2f(*(const short*)(c2l+qo));
  for (int m=1; m<64; m<<=1) qs += __shfl_xor(qs, m);
  float dn = __expf(rowt[bt]) * qs;
  for (int p=0; p<4; p++) dn += denp[bt*4 + p];
  dn = fmaxf(fabsf(dn), 1.f);
  float nv = num[bt*64 + d];
  size_t io = (size_t)row*N3 + 512 + h*64 + d;
  float ov = bfbits2f(*(const short*)(c3h+io)) + bfbits2f(*(const short*)(c3l+io));
  float o = 1.f/(1.f + __expf(-ov));
  float hv = o * nv / dn;
  float s = hv, ss = hv*hv;
  for (int m=1; m<64; m<<=1){ s += __shfl_xor(s,m); ss += __shfl_xor(ss,m); }
  float mu = s*(1.f/64.f), var = ss*(1.f/64.f) - mu*mu;
  float gn = (hv - mu)*rsqrtf(var + EPSV)*gng[h*64+d] + gnb[h*64+d];
  size_t ks = (size_t)row*N2 + 1024 + h*64 + d;
  float sk = bfbits2f(*(const short*)(c2h+ks)) + bfbits2f(*(const short*)(c2l+ks));
  size_t kr = (size_t)row*N1 + 1024 + h*64 + d;
  float rv = bfbits2f(*(const short*)(c1h+kr)) + bfbits2f(*(const short*)(c1l+kr));
  float y = (gn + sk) * (rv/(1.f + __expf(-rv)));
  size_t oo = (size_t)row*512 + h*64 + d;
  split_bf(y, oph[oo], opl[oo]);
}

// ===================== host =====================
extern "C" void kernel_launch(void* const* d_in, const int* in_sizes, int n_in,
                              void* d_out, int out_size, void* d_ws, size_t ws_size,
                              hipStream_t stream)
{
  (void)in_sizes; (void)n_in; (void)out_size; (void)ws_size;
  const float* seq    = (const float*)d_in[0];
  const float* ln_g   = (const float*)d_in[1];
  const float* ln_b   = (const float*)d_in[2];
  const float* upl_w  = (const float*)d_in[3];
  const float* upl_b  = (const float*)d_in[4];
  const float* upr_w  = (const float*)d_in[5];
  const float* upr_b  = (const float*)d_in[6];
  const float* conv_w = (const float*)d_in[7];
  const float* conv_b = (const float*)d_in[8];
  const float* wq_w   = (const float*)d_in[9];
  const float* wq_b   = (const float*)d_in[10];
  const float* wk_w   = (const float*)d_in[11];
  const float* wk_b   = (const float*)d_in[12];
  const float* wv_w   = (const float*)d_in[13];
  const float* wv_b   = (const float*)d_in[14];
  const float* wo_w   = (const float*)d_in[15];
  const float* wo_b   = (const float*)d_in[16];
  const float* wi_w   = (const float*)d_in[17];
  const float* wi_b   = (const float*)d_in[18];
  const float* wf_w   = (const float*)d_in[19];
  const float* wf_b   = (const float*)d_in[20];
  const float* skip_w = (const float*)d_in[21];
  const float* gn_g   = (const float*)d_in[22];
  const float* gn_b   = (const float*)d_in[23];
  const float* down_w = (const float*)d_in[24];
  const float* down_b = (const float*)d_in[25];

  char* ws = (char*)d_ws;
  size_t off = 0;
  auto alloc = [&](size_t bytes)->char*{
    char* p = ws + off; off = (off + bytes + 255) & ~(size_t)255; return p;
  };
  bf16*  W1h = (bf16*)alloc((size_t)3*N1*512*2);
  bf16*  W1l = (bf16*)alloc((size_t)3*N1*512*2);
  bf16*  W2h = (bf16*)alloc((size_t)3*N2*1024*2);
  bf16*  W2l = (bf16*)alloc((size_t)3*N2*1024*2);
  bf16*  W3h = (bf16*)alloc((size_t)3*N3*1024*2);
  bf16*  W3l = (bf16*)alloc((size_t)3*N3*1024*2);
  bf16*  W4h = (bf16*)alloc((size_t)3*512*512*2);
  bf16*  W4l = (bf16*)alloc((size_t)3*512*512*2);
  float* b1  = (float*)alloc((size_t)3*N1*4);
  float* b2  = (float*)alloc((size_t)3*N2*4);
  float* b3  = (float*)alloc((size_t)3*N3*4);
  float* b4  = (float*)alloc((size_t)3*512*4);
  bf16*  xnh = (bf16*)alloc((size_t)NROW*512*2);
  bf16*  xnl = (bf16*)alloc((size_t)NROW*512*2);
  bf16*  c1h = (bf16*)alloc((size_t)NROW*N1*2);
  bf16*  c1l = (bf16*)alloc((size_t)NROW*N1*2);
  bf16*  xch = (bf16*)alloc((size_t)NROW*1024*2);
  bf16*  xcl = (bf16*)alloc((size_t)NROW*1024*2);
  bf16*  c2h = (bf16*)alloc((size_t)NROW*N2*2);
  bf16*  c2l = (bf16*)alloc((size_t)NROW*N2*2);
  bf16*  c3h = (bf16*)alloc((size_t)NROW*N3*2);
  bf16*  c3l = (bf16*)alloc((size_t)NROW*N3*2);
  bf16*  vTh = (bf16*)alloc((size_t)32*64*512*2);
  bf16*  vTl = (bf16*)alloc((size_t)32*64*512*2);
  float* rowt= (float*)alloc((size_t)32*512*4);
  float* colt= (float*)alloc((size_t)32*512*4);
  float* denp= (float*)alloc((size_t)32*512*4*4);
  float* num = (float*)alloc((size_t)32*512*64*4);
  bf16*  oph = (bf16*)alloc((size_t)NROW*512*2);
  bf16*  opl = (bf16*)alloc((size_t)NROW*512*2);
  float* xA  = (float*)alloc((size_t)NROW*512*4);
  float* xB  = (float*)alloc((size_t)NROW*512*4);

  // --- pack all weights/biases to hi/lo bf16 (k-scale folded) in ONE dispatch ---
  pack_all<<<dim3(3713,3), 256, 0, stream>>>(
      upl_w, upr_w, wq_w, wk_w, skip_w, wi_w, wf_w, wv_w, wo_w, down_w,
      upl_b, upr_b, wq_b, wk_b, wi_b, wf_b, wv_b, wo_b, down_b,
      W1h, W1l, W2h, W2l, W3h, W3l, W4h, W4l, b1, b2, b3, b4);

  for (int l = 0; l < 3; l++){
    const float* x_in = (l == 0) ? seq : ((l == 1) ? xA : xB);
    float* x_out = (l == 0) ? xA : ((l == 1) ? xB : (float*)d_out);

    ln_kernel<<<NROW, 256, 0, stream>>>(x_in, ln_g + l*512, ln_b + l*512, xnh, xnl);
    gemm_s64<<<32*12, 256, 0, stream>>>(
        xnh, xnl, W1h + (size_t)l*N1*512, W1l + (size_t)l*N1*512,
        b1 + l*N1, nullptr, c1h, c1l, nullptr, N1, 512, 512, 12);
    conv_kernel<<<NROW, 256, 0, stream>>>(c1h, c1l, conv_w + l*4, conv_b + l,
                                          xch, xcl);
    gemm23<<<21*16, 512, 0, stream>>>(
        xch, xcl, W2h + (size_t)l*N2*1024, W2l + (size_t)l*N2*1024, b2 + l*N2,
        c2h, c2l,
        c1h, c1l, W3h + (size_t)l*N3*1024, W3l + (size_t)l*N3*1024, b3 + l*N3,
        c3h, c3l);
    prep_kernel<<<dim3(9,32), 512, 0, stream>>>(c3h, c3l, c2h, c2l,
                                                vTh, vTl, rowt, colt);
    attn_kernel<<<dim3(16,32), 256, 0, stream>>>(c2h, c2l, vTh, vTl,
                                                 rowt, colt, num, denp);
    h_kernel<<<NROW, 512, 0, stream>>>(num, denp, rowt, c2h, c2l, c3h, c3l,
                                       c1h, c1l, gn_g + l*512, gn_b + l*512,
                                       oph, opl);
    gemm_s64<<<32*4, 256, 0, stream>>>(
        oph, opl, W4h + (size_t)l*512*512, W4l + (size_t)l*512*512,
        b4 + l*512, x_out, nullptr, nullptr, x_in, 512, 512, 512, 4);
  }
}

// Round 13
// 376.135 us; speedup vs baseline: 1.1458x; 1.0308x over previous
//
#include <hip/hip_runtime.h>
#include <hip/hip_bf16.h>
#include <cstdint>
#include <cstddef>

typedef short short8 __attribute__((ext_vector_type(8)));
typedef short short4v __attribute__((ext_vector_type(4)));
typedef float f32x4 __attribute__((ext_vector_type(4)));
typedef __hip_bfloat16 bf16;

#define NROW 2048      // S*B rows
#define N1 1536        // [upl(1024); upr(512)]
#define N2 1664        // [wq(512); wk(512); skip(512); wi(8); wf(8); pad(112)]
#define N3 1024        // [wv(512); wo(512)]
#define EPSV 1e-5f

static __device__ __forceinline__ bf16 f2bf(float v){ return __float2bfloat16(v); }
static __device__ __forceinline__ float bfbits2f(short s){
  unsigned u = ((unsigned)(unsigned short)s) << 16;
  float f; __builtin_memcpy(&f, &u, 4); return f;
}
static __device__ __forceinline__ void split_bf(float v, bf16& h, bf16& l){
  h = __float2bfloat16(v);
  l = __float2bfloat16(v - __bfloat162float(h));
}

static __device__ __forceinline__ void gload16(const bf16* g, bf16* l){
  __builtin_amdgcn_global_load_lds(
      (const __attribute__((address_space(1))) void*)(g),
      (__attribute__((address_space(3))) void*)(l), 16, 0, 0);
}

#define MFMA __builtin_amdgcn_mfma_f32_16x16x32_bf16

// ===================== single mega weight/bias pack kernel (vectorized) =====================
// W1: 768 blocks (2 rows each) | W2: 1664 | W3: 1024 | W4: 256 (2 rows) | bias: 1
__global__ __launch_bounds__(256) void pack_all(
    const float* __restrict__ upl, const float* __restrict__ upr,
    const float* __restrict__ wq,  const float* __restrict__ wk,
    const float* __restrict__ skp, const float* __restrict__ wi,
    const float* __restrict__ wf,  const float* __restrict__ wv,
    const float* __restrict__ wo,  const float* __restrict__ dw,
    const float* __restrict__ uplb, const float* __restrict__ uprb,
    const float* __restrict__ wqb,  const float* __restrict__ wkb,
    const float* __restrict__ wib,  const float* __restrict__ wfb,
    const float* __restrict__ wvb,  const float* __restrict__ wob,
    const float* __restrict__ dwb,
    bf16* __restrict__ W1h, bf16* __restrict__ W1l,
    bf16* __restrict__ W2h, bf16* __restrict__ W2l,
    bf16* __restrict__ W3h, bf16* __restrict__ W3l,
    bf16* __restrict__ W4h, bf16* __restrict__ W4l,
    float* __restrict__ b1, float* __restrict__ b2,
    float* __restrict__ b3, float* __restrict__ b4)
{
  int l = blockIdx.y;
  int bx = blockIdx.x;
  if (bx < 768){                        // ---- W1: [upl(1024); upr(512)], K=512, 2 rows/block
    int r = bx*2 + (threadIdx.x >> 7);
    int c4 = threadIdx.x & 127;
    const float* src = (r < 1024) ? upl + ((size_t)l*1024 + r)*512
                                  : upr + ((size_t)l*512 + (r-1024))*512;
    size_t o = ((size_t)l*N1 + r)*512 + c4*4;
    f32x4 v = *(const f32x4*)(src + c4*4);
    short4v hh, ll;
    for (int e=0;e<4;e++){ bf16 h_,l_; split_bf(v[e],h_,l_);
      hh[e] = *(short*)&h_; ll[e] = *(short*)&l_; }
    *(short4v*)(W1h+o) = hh; *(short4v*)(W1l+o) = ll;
  } else if (bx < 2432){                // ---- W2, K=1024
    int r = bx - 768;
    int c4 = threadIdx.x;
    const float* src; float sc = 1.f;
    if (r < 512)        src = wq  + ((size_t)l*512 + r)*1024;
    else if (r < 1024){ src = wk  + ((size_t)l*512 + r-512)*1024; sc = 0.125f; }
    else if (r < 1536)  src = skp + ((size_t)l*512 + r-1024)*1024;
    else if (r < 1544)  src = wi  + ((size_t)l*8   + r-1536)*1024;
    else if (r < 1552)  src = wf  + ((size_t)l*8   + r-1544)*1024;
    else src = nullptr;
    size_t o = ((size_t)l*N2 + r)*1024 + c4*4;
    f32x4 v = src ? *(const f32x4*)(src + c4*4) : (f32x4){0.f,0.f,0.f,0.f};
    short4v hh, ll;
    for (int e=0;e<4;e++){ bf16 h_,l_; split_bf(v[e]*sc,h_,l_);
      hh[e] = *(short*)&h_; ll[e] = *(short*)&l_; }
    *(short4v*)(W2h+o) = hh; *(short4v*)(W2l+o) = ll;
  } else if (bx < 3456){                // ---- W3: [wv; wo], K=1024
    int r = bx - 2432;
    int c4 = threadIdx.x;
    const float* src = (r < 512) ? wv + ((size_t)l*512 + r)*1024
                                 : wo + ((size_t)l*512 + (r-512))*1024;
    size_t o = ((size_t)l*N3 + r)*1024 + c4*4;
    f32x4 v = *(const f32x4*)(src + c4*4);
    short4v hh, ll;
    for (int e=0;e<4;e++){ bf16 h_,l_; split_bf(v[e],h_,l_);
      hh[e] = *(short*)&h_; ll[e] = *(short*)&l_; }
    *(short4v*)(W3h+o) = hh; *(short4v*)(W3l+o) = ll;
  } else if (bx < 3712){                // ---- W4 (down), K=512, 2 rows/block
    int r = (bx - 3456)*2 + (threadIdx.x >> 7);
    int c4 = threadIdx.x & 127;
    const float* src = dw + ((size_t)l*512 + r)*512;
    size_t o = ((size_t)l*512 + r)*512 + c4*4;
    f32x4 v = *(const f32x4*)(src + c4*4);
    short4v hh, ll;
    for (int e=0;e<4;e++){ bf16 h_,l_; split_bf(v[e],h_,l_);
      hh[e] = *(short*)&h_; ll[e] = *(short*)&l_; }
    *(short4v*)(W4h+o) = hh; *(short4v*)(W4l+o) = ll;
  } else {                              // ---- biases
    for (int j = threadIdx.x; j < N1; j += 256)
      b1[l*N1+j] = (j < 1024) ? uplb[l*1024+j] : uprb[l*512+j-1024];
    for (int j = threadIdx.x; j < N2; j += 256){
      float v = 0.f;
      if (j < 512)        v = wqb[l*512+j];
      else if (j < 1024)  v = wkb[l*512+j-512]*0.125f;
      else if (j < 1536)  v = 0.f;
      else if (j < 1544)  v = wib[l*8+j-1536];
      else if (j < 1552)  v = wfb[l*8+j-1544];
      b2[l*N2+j] = v;
    }
    for (int j = threadIdx.x; j < N3; j += 256)
      b3[l*N3+j] = (j < 512) ? wvb[l*512+j] : wob[l*512+j-512];
    for (int j = threadIdx.x; j < 512; j += 256)
      b4[l*512+j] = dwb[l*512+j];
  }
}

// ===================== LDS-staged split-bf16 GEMM core (128x128, 8 waves) =====================
static __device__ __forceinline__ void gemm_core(
    bf16* __restrict__ sm,        // 2 bufs x [Ah|Al|Bh|Bl] x 4096 bf16
    int bx, int by,
    const bf16* __restrict__ Ah, const bf16* __restrict__ Al,
    const bf16* __restrict__ Wh, const bf16* __restrict__ Wl,
    const float* __restrict__ bias, float* __restrict__ Cf,
    bf16* __restrict__ Cbh, bf16* __restrict__ Cbl,
    const float* __restrict__ resid, int N, int K, int lda)
{
  int tid = threadIdx.x;
  int lane = tid & 63, w = tid >> 6;
  int wr = w >> 2, wc = w & 3;            // 2 x 4 waves, each 64(M) x 32(N)
  int m0 = by*128, n0 = bx*128;
  int srow = tid >> 2, sslot = tid & 3;   // coalesced: 4 lanes per 64B row
  int gcol = ((sslot ^ (srow & 3)) * 8);  // pre-swizzled global slot
  const bf16* gAh = Ah + (size_t)(m0 + srow)*lda + gcol;
  const bf16* gAl = Al + (size_t)(m0 + srow)*lda + gcol;
  const bf16* gBh = Wh + (size_t)(n0 + srow)*K + gcol;
  const bf16* gBl = Wl + (size_t)(n0 + srow)*K + gcol;

  f32x4 acc[4][2];
  for (int i=0;i<4;i++) for (int j=0;j<2;j++) acc[i][j] = (f32x4){0.f,0.f,0.f,0.f};

  int r = lane & 15, g = lane >> 4;
  int xs = (g ^ (r & 3)) * 8;             // swizzled read slot
  int aoff[4], boff[2];
  for (int mi=0;mi<4;mi++) aoff[mi] = (wr*64 + mi*16 + r)*32 + xs;
  for (int ni=0;ni<2;ni++) boff[ni] = (wc*32 + ni*16 + r)*32 + xs;

  int nt = K >> 5;
#define STAGE_T(base, kk) do{ bf16* _d = sm + (base) + tid*8; \
    gload16(gAh + (kk), _d); \
    gload16(gAl + (kk), _d + 4096); \
    gload16(gBh + (kk), _d + 8192); \
    gload16(gBl + (kk), _d + 12288); }while(0)

  STAGE_T(0, 0);
  asm volatile("s_waitcnt vmcnt(0)" ::: "memory");
  __builtin_amdgcn_s_barrier();

  for (int t = 0; t < nt; ++t){
    int cb = (t & 1) * 16384;
    if (t + 1 < nt) STAGE_T(16384 - cb, (t+1)*32);
    const bf16* sA = sm + cb;
    short8 ah[4], al[4], bh2[2], bl2[2];
    for (int mi=0;mi<4;mi++){
      ah[mi] = *(const short8*)(sA + aoff[mi]);
      al[mi] = *(const short8*)(sA + 4096 + aoff[mi]);
    }
    for (int ni=0;ni<2;ni++){
      bh2[ni] = *(const short8*)(sA + 8192 + boff[ni]);
      bl2[ni] = *(const short8*)(sA + 12288 + boff[ni]);
    }
    for (int mi=0;mi<4;mi++) for (int ni=0;ni<2;ni++)
      acc[mi][ni] = MFMA(ah[mi], bh2[ni], acc[mi][ni],0,0,0);
    for (int mi=0;mi<4;mi++) for (int ni=0;ni<2;ni++)
      acc[mi][ni] = MFMA(al[mi], bh2[ni], acc[mi][ni],0,0,0);
    for (int mi=0;mi<4;mi++) for (int ni=0;ni<2;ni++)
      acc[mi][ni] = MFMA(ah[mi], bl2[ni], acc[mi][ni],0,0,0);
    asm volatile("s_waitcnt vmcnt(0)" ::: "memory");
    __builtin_amdgcn_s_barrier();
  }
#undef STAGE_T

  for (int mi=0;mi<4;mi++) for (int ni=0;ni<2;ni++){
    int col = n0 + wc*32 + ni*16 + r;
    float bv = bias ? bias[col] : 0.f;
    for (int j=0;j<4;j++){
      int row = m0 + wr*64 + mi*16 + g*4 + j;
      float v = acc[mi][ni][j] + bv;
      size_t o = (size_t)row*N + col;
      if (resid) v += resid[o];
      if (Cf) Cf[o] = v;
      if (Cbh) split_bf(v, Cbh[o], Cbl[o]);
    }
  }
}

// ===================== 64x128-tile GEMM core (256 thr, 4 waves, 48KB LDS) =====================
static __device__ __forceinline__ void gemm_core64(
    bf16* __restrict__ sm,        // 2 bufs x [Ah(2048)|Al(2048)|Bh(4096)|Bl(4096)]
    int bx, int by,
    const bf16* __restrict__ Ah, const bf16* __restrict__ Al,
    const bf16* __restrict__ Wh, const bf16* __restrict__ Wl,
    const float* __restrict__ bias, float* __restrict__ Cf,
    bf16* __restrict__ Cbh, bf16* __restrict__ Cbl,
    const float* __restrict__ resid, int N, int K, int lda)
{
  int tid = threadIdx.x;                  // 256 threads, 4 waves
  int lane = tid & 63, w = tid >> 6;      // wave w covers cols w*32..+31
  int m0 = by*64, n0 = bx*128;
  int srow = tid >> 2, sslot = tid & 3;
  int gcol = ((sslot ^ (srow & 3)) * 8);
  const bf16* gAh = Ah + (size_t)(m0 + srow)*lda + gcol;
  const bf16* gAl = Al + (size_t)(m0 + srow)*lda + gcol;
  const bf16* gBh = Wh + (size_t)(n0 + srow)*K + gcol;
  const bf16* gBl = Wl + (size_t)(n0 + srow)*K + gcol;
  size_t pstr = (size_t)64*K;             // B rows 64..127

  f32x4 acc[4][2];
  for (int i=0;i<4;i++) for (int j=0;j<2;j++) acc[i][j] = (f32x4){0.f,0.f,0.f,0.f};

  int r = lane & 15, g = lane >> 4;
  int xs = (g ^ (r & 3)) * 8;
  int aoff[4], boff[2];
  for (int mi=0;mi<4;mi++) aoff[mi] = (mi*16 + r)*32 + xs;
  for (int ni=0;ni<2;ni++) boff[ni] = (w*32 + ni*16 + r)*32 + xs;

  int nt = K >> 5;
#define STAGE64(base, kk) do{ bf16* _d = sm + (base) + tid*8; \
    gload16(gAh + (kk), _d); \
    gload16(gAl + (kk), _d + 2048); \
    gload16(gBh + (kk), _d + 4096);  gload16(gBh + (kk) + pstr, _d + 6144); \
    gload16(gBl + (kk), _d + 8192);  gload16(gBl + (kk) + pstr, _d + 10240); }while(0)

  STAGE64(0, 0);
  asm volatile("s_waitcnt vmcnt(0)" ::: "memory");
  __builtin_amdgcn_s_barrier();

  for (int t = 0; t < nt; ++t){
    int cb = (t & 1) * 12288;
    if (t + 1 < nt) STAGE64(12288 - cb, (t+1)*32);
    const bf16* sA = sm + cb;
    short8 ah[4], al[4], bh2[2], bl2[2];
    for (int mi=0;mi<4;mi++){
      ah[mi] = *(const short8*)(sA + aoff[mi]);
      al[mi] = *(const short8*)(sA + 2048 + aoff[mi]);
    }
    for (int ni=0;ni<2;ni++){
      bh2[ni] = *(const short8*)(sA + 4096 + boff[ni]);
      bl2[ni] = *(const short8*)(sA + 8192 + boff[ni]);
    }
    for (int mi=0;mi<4;mi++) for (int ni=0;ni<2;ni++)
      acc[mi][ni] = MFMA(ah[mi], bh2[ni], acc[mi][ni],0,0,0);
    for (int mi=0;mi<4;mi++) for (int ni=0;ni<2;ni++)
      acc[mi][ni] = MFMA(al[mi], bh2[ni], acc[mi][ni],0,0,0);
    for (int mi=0;mi<4;mi++) for (int ni=0;ni<2;ni++)
      acc[mi][ni] = MFMA(ah[mi], bl2[ni], acc[mi][ni],0,0,0);
    asm volatile("s_waitcnt vmcnt(0)" ::: "memory");
    __builtin_amdgcn_s_barrier();
  }
#undef STAGE64

  for (int mi=0;mi<4;mi++) for (int ni=0;ni<2;ni++){
    int col = n0 + w*32 + ni*16 + r;
    float bv = bias ? bias[col] : 0.f;
    for (int j=0;j<4;j++){
      int row = m0 + mi*16 + g*4 + j;
      float v = acc[mi][ni][j] + bv;
      size_t o = (size_t)row*N + col;
      if (resid) v += resid[o];
      if (Cf) Cf[o] = v;
      if (Cbh) split_bf(v, Cbh[o], Cbl[o]);
    }
  }
}

// standalone small GEMM (64x128): 1D grid (divisible by 8), XCD swizzle
__global__ __launch_bounds__(256) void gemm_s64(
    const bf16* __restrict__ Ah, const bf16* __restrict__ Al,
    const bf16* __restrict__ Wh, const bf16* __restrict__ Wl,
    const float* __restrict__ bias, float* __restrict__ Cf,
    bf16* __restrict__ Cbh, bf16* __restrict__ Cbl,
    const float* __restrict__ resid, int N, int K, int lda, int nbx)
{
  __shared__ bf16 sm[2*12288];
  int id = blockIdx.x;
  int cpx = gridDim.x >> 3;
  int swz = (id & 7)*cpx + (id >> 3);
  int by = swz / nbx, bx = swz - by*nbx;
  gemm_core64(sm, bx, by, Ah, Al, Wh, Wl, bias, Cf, Cbh, Cbl, resid, N, K, lda);
}

// fused gemm2+gemm3 (both K=1024): bx<13 -> set2 (N2), else set3 (N3, A=c1 via lda)
__global__ __launch_bounds__(512) void gemm23(
    const bf16* __restrict__ A2h, const bf16* __restrict__ A2l,
    const bf16* __restrict__ W2h, const bf16* __restrict__ W2l,
    const float* __restrict__ b2,
    bf16* __restrict__ c2h, bf16* __restrict__ c2l,
    const bf16* __restrict__ A3h, const bf16* __restrict__ A3l,
    const bf16* __restrict__ W3h, const bf16* __restrict__ W3l,
    const float* __restrict__ b3,
    bf16* __restrict__ c3h, bf16* __restrict__ c3l)
{
  __shared__ bf16 sm[2*4*4096];
  int id = blockIdx.x;
  int cpx = gridDim.x >> 3;          // 336/8 = 42
  int swz = (id & 7)*cpx + (id >> 3);
  int by = swz / 21, bx = swz - by*21;
  if (bx < 13)
    gemm_core(sm, bx, by, A2h, A2l, W2h, W2l, b2, nullptr, c2h, c2l,
              nullptr, N2, 1024, 1024);
  else
    gemm_core(sm, bx-13, by, A3h, A3l, W3h, W3l, b3, nullptr, c3h, c3l,
              nullptr, N3, 1024, N1);
}

// ===================== LayerNorm (fp32 in -> hi/lo bf16 out) =====================
__global__ __launch_bounds__(256) void ln_kernel(const float* __restrict__ x,
    const float* __restrict__ g, const float* __restrict__ bt,
    bf16* __restrict__ xnh, bf16* __restrict__ xnl)
{
  int row = blockIdx.x, t = threadIdx.x;
  float v0 = x[(size_t)row*512 + t], v1 = x[(size_t)row*512 + 256 + t];
  float s = v0 + v1, ss = v0*v0 + v1*v1;
  for (int m=1; m<64; m<<=1){ s += __shfl_xor(s,m); ss += __shfl_xor(ss,m); }
  __shared__ float sh[8];
  int w = t >> 6, lane = t & 63;
  if (lane == 0){ sh[w] = s; sh[4+w] = ss; }
  __syncthreads();
  s = sh[0]+sh[1]+sh[2]+sh[3]; ss = sh[4]+sh[5]+sh[6]+sh[7];
  float mu = s*(1.f/512.f), var = ss*(1.f/512.f) - mu*mu;
  float rs = rsqrtf(var + EPSV);
  float y0 = (v0-mu)*rs*g[t]     + bt[t];
  float y1 = (v1-mu)*rs*g[256+t] + bt[256+t];
  split_bf(y0, xnh[(size_t)row*512 + t],       xnl[(size_t)row*512 + t]);
  split_bf(y1, xnh[(size_t)row*512 + 256 + t], xnl[(size_t)row*512 + 256 + t]);
}

// ===================== causal conv + silu; reads c1 hi/lo, writes x_c hi/lo only =====================
__global__ __launch_bounds__(256) void conv_kernel(
    const bf16* __restrict__ c1h, const bf16* __restrict__ c1l,
    const float* __restrict__ cw, const float* __restrict__ cb,
    bf16* __restrict__ xch, bf16* __restrict__ xcl)
{
  int row = blockIdx.x;
  size_t rb = (size_t)row*N1;
  float w0=cw[0], w1=cw[1], w2=cw[2], w3=cw[3], bb=cb[0];
  int j0 = threadIdx.x*4;          // 0..1023, 4 consecutive outputs
  float x[7];
  for (int k=0;k<3;k++){
    int j = j0-3+k;
    x[k] = (j>=0) ? (bfbits2f(*(const short*)(c1h+rb+j)) +
                     bfbits2f(*(const short*)(c1l+rb+j))) : 0.f;
  }
  short4v h4 = *(const short4v*)(c1h+rb+j0);
  short4v l4 = *(const short4v*)(c1l+rb+j0);
  for (int k=0;k<4;k++) x[3+k] = bfbits2f(h4[k]) + bfbits2f(l4[k]);
  for (int i=0;i<4;i++){
    float y = bb + w0*x[i] + w1*x[i+1] + w2*x[i+2] + w3*x[i+3];
    float sg = 1.f/(1.f + __expf(-y));
    size_t o = (size_t)row*1024 + j0 + i;
    split_bf(y*sg, xch[o], xcl[o]);
  }
}

// ===================== prep: LDS-transposed vtrans (bx<8) + gate scan (bx==8) =====================
__global__ __launch_bounds__(512) void prep_kernel(
    const bf16* __restrict__ c3h, const bf16* __restrict__ c3l,
    const bf16* __restrict__ c2h, const bf16* __restrict__ c2l,
    bf16* __restrict__ vTh, bf16* __restrict__ vTl,
    float* __restrict__ rowt, float* __restrict__ colt)
{
  int bh = blockIdx.y, b = bh >> 3, h = bh & 7;
  if (blockIdx.x < 8){
    // ---- vtrans tile: s in [s0, s0+64), all 64 d; coalesced both sides via LDS
    __shared__ short th[64*66], tl[64*66];
    int s0 = blockIdx.x*64;
    int sl = threadIdx.x >> 3, d8 = (threadIdx.x & 7)*8;
    size_t i = (size_t)((s0+sl)*4+b)*N3 + h*64 + d8;
    short8 hv = *(const short8*)(c3h+i);
    short8 lv = *(const short8*)(c3l+i);
    for (int e=0;e<8;e++){
      th[sl*66 + d8+e] = hv[e];
      tl[sl*66 + d8+e] = lv[e];
    }
    __syncthreads();
    int dl = threadIdx.x >> 3, s8 = (threadIdx.x & 7)*8;
    short8 oh, ol;
    for (int e=0;e<8;e++){
      oh[e] = th[(s8+e)*66 + dl];
      ol[e] = tl[(s8+e)*66 + dl];
    }
    size_t o = ((size_t)bh*64 + dl)*512 + s0 + s8;
    *(short8*)(vTh+o) = oh;
    *(short8*)(vTl+o) = ol;
    return;
  }
  // ---- barrier-free per-wave scan (fp64 sum, fp32 max), first wave only
  if (threadIdx.x >= 64) return;
  int lane = threadIdx.x;
  double fv[8]; float iv[8];
  for (int j=0;j<8;j++){
    int t = lane*8 + j;
    size_t ro = (size_t)(t*4+b)*N2;
    fv[j] = (double)(bfbits2f(*(const short*)(c2h+ro+1544+h)) +
                     bfbits2f(*(const short*)(c2l+ro+1544+h)));
    iv[j] = bfbits2f(*(const short*)(c2h+ro+1536+h)) +
            bfbits2f(*(const short*)(c2l+ro+1536+h));
  }
  double ps[8]; double s = 0.0;
  for (int j=0;j<8;j++){ s += fv[j]; ps[j] = s; }
  double run = s;
  for (int o=1;o<64;o<<=1){
    double u = __shfl_up(run, o);
    if (lane >= o) run += u;
  }
  double excl = run - s;
  float ct[8];
  for (int j=0;j<8;j++){
    ct[j] = (float)((double)iv[j] - (excl + ps[j]));
    colt[bh*512 + lane*8 + j] = ct[j];
  }
  float pm[8]; float mm = -3.0e38f;
  for (int j=0;j<8;j++){ mm = fmaxf(mm, ct[j]); pm[j] = mm; }
  float incl = mm;
  for (int o=1;o<64;o<<=1){
    float u = __shfl_up(incl, o);
    if (lane >= o) incl = fmaxf(incl, u);
  }
  float ex = __shfl_up(incl, 1);
  if (lane == 0) ex = -3.0e38f;
  for (int j=0;j<8;j++){
    float inc = fmaxf(ex, pm[j]);
    rowt[bh*512 + lane*8 + j] = -fmaxf(0.f, inc);   // = A_t - m_t (<= 0)
  }
}

// ===================== fused attention + h: QK^T -> decay/mask -> PV -> den -> h/GN/out =====================
// grid (16, 32 bh) with balanced tb pairing; 256 thr (4 waves). The h-phase
// (o*num/den, GroupNorm, +skip, *silu(r)) runs in-block via LDS transposition.
__global__ __launch_bounds__(256) void attn_kernel(
    const bf16* __restrict__ c2h, const bf16* __restrict__ c2l,
    const bf16* __restrict__ vTh, const bf16* __restrict__ vTl,
    const float* __restrict__ rowt, const float* __restrict__ colt,
    const bf16* __restrict__ c3h, const bf16* __restrict__ c3l,
    const bf16* __restrict__ c1h, const bf16* __restrict__ c1l,
    const float* __restrict__ gng, const float* __restrict__ gnb,
    bf16* __restrict__ oph, bf16* __restrict__ opl)
{
  __shared__ bf16 Ph[32*64], Pl[32*64];
  __shared__ float cts[512];
  __shared__ float numS[32][64];
  __shared__ float denS[32][4];
  __shared__ float qsS[32];
  int lane = threadIdx.x & 63, w = threadIdx.x >> 6;
  int x = blockIdx.x;
  int tb = (x & 1) ? (15 - (x >> 1)) : (x >> 1);   // balanced pairs (sum const)
  int bh = blockIdx.y, b = bh >> 3, h = bh & 7;
  int t0 = tb*32;

  // load colterm into LDS (coalesced)
  cts[threadIdx.x]       = colt[bh*512 + threadIdx.x];
  cts[256 + threadIdx.x] = colt[bh*512 + 256 + threadIdx.x];

  int r = lane & 15, g = lane >> 4;
  int rq = g*4;

  short8 qh[2][2], ql[2][2];
  for (int mi=0;mi<2;mi++) for (int k0=0;k0<2;k0++){
    size_t off = (size_t)((t0+mi*16+r)*4+b)*N2 + h*64 + k0*32 + g*8;
    qh[mi][k0] = *(const short8*)(c2h+off);
    ql[mi][k0] = *(const short8*)(c2l+off);
  }
  // q row-sums for den0 (all 4 waves hold identical Q; wave 0 publishes)
  for (int mi=0;mi<2;mi++){
    float qp = 0.f;
    for (int k0=0;k0<2;k0++)
      for (int e=0;e<8;e++)
        qp += bfbits2f(qh[mi][k0][e]) + bfbits2f(ql[mi][k0][e]);
    qp += __shfl_xor(qp, 16);
    qp += __shfl_xor(qp, 32);
    if (w == 0 && g == 0) qsS[mi*16 + r] = qp;
  }
  float rtv[2][4];
  for (int mi=0;mi<2;mi++) for (int j=0;j<4;j++)
    rtv[mi][j] = rowt[bh*512 + t0 + mi*16 + rq + j];
  __syncthreads();

  f32x4 accPV[2];
  for (int i=0;i<2;i++) accPV[i] = (f32x4){0.f,0.f,0.f,0.f};
  float rsum[2][4];
  for (int i=0;i<2;i++) for (int j=0;j<4;j++) rsum[i][j] = 0.f;

  int nsb = (tb >> 1) + 1;
  for (int sb=0; sb<nsb; ++sb){
    int s0 = sb*64;
    f32x4 acc[2];
    for (int i=0;i<2;i++) acc[i] = (f32x4){0.f,0.f,0.f,0.f};
    short8 kh[2], kl[2];
    for (int k0=0;k0<2;k0++){
      size_t off = (size_t)((s0+w*16+r)*4+b)*N2 + 512 + h*64 + k0*32 + g*8;
      kh[k0] = *(const short8*)(c2h+off);
      kl[k0] = *(const short8*)(c2l+off);
    }
    for (int k0=0;k0<2;k0++){
      for (int mi=0;mi<2;mi++) acc[mi] = MFMA(qh[mi][k0], kh[k0], acc[mi],0,0,0);
      for (int mi=0;mi<2;mi++) acc[mi] = MFMA(ql[mi][k0], kh[k0], acc[mi],0,0,0);
      for (int mi=0;mi<2;mi++) acc[mi] = MFMA(qh[mi][k0], kl[k0], acc[mi],0,0,0);
    }
    int sl = w*16 + r;
    int s = s0 + sl;
    float ctv = cts[s];
    for (int mi=0;mi<2;mi++){
      for (int j=0;j<4;j++){
        int tloc = mi*16 + rq + j;
        int t = t0 + tloc;
        float wg = (s <= t) ? __expf(rtv[mi][j] + ctv) : 0.f;
        float gv = acc[mi][j] * wg;
        rsum[mi][j] += gv;
        int col = ((((sl>>3) ^ (tloc&7))<<3) | (sl&7));
        split_bf(gv, Ph[tloc*64+col], Pl[tloc*64+col]);
      }
    }
    __syncthreads();
    short8 vh[2], vl[2];
    for (int k0=0;k0<2;k0++){
      size_t off = ((size_t)bh*64 + w*16 + r)*512 + s0 + k0*32 + g*8;
      vh[k0] = *(const short8*)(vTh+off);
      vl[k0] = *(const short8*)(vTl+off);
    }
    for (int k0=0;k0<2;k0++){
      short8 ph[2], pl[2];
      for (int mi=0;mi<2;mi++){
        int tloc = mi*16 + r;
        int slot = (k0*4 + g) ^ (tloc&7);
        ph[mi] = *(const short8*)(&Ph[tloc*64 + slot*8]);
        pl[mi] = *(const short8*)(&Pl[tloc*64 + slot*8]);
      }
      for (int mi=0;mi<2;mi++) accPV[mi] = MFMA(ph[mi], vh[k0], accPV[mi],0,0,0);
      for (int mi=0;mi<2;mi++) accPV[mi] = MFMA(pl[mi], vh[k0], accPV[mi],0,0,0);
      for (int mi=0;mi<2;mi++) accPV[mi] = MFMA(ph[mi], vl[k0], accPV[mi],0,0,0);
    }
    __syncthreads();
  }

  // publish num + den partials to LDS
  for (int mi=0;mi<2;mi++)
    for (int j=0;j<4;j++)
      numS[mi*16 + rq + j][w*16 + r] = accPV[mi][j];
  for (int mi=0;mi<2;mi++)
    for (int j=0;j<4;j++){
      float v = rsum[mi][j];
      v += __shfl_xor(v,1); v += __shfl_xor(v,2);
      v += __shfl_xor(v,4); v += __shfl_xor(v,8);
      if (r == 0) denS[mi*16 + rq + j][w] = v;
    }
  __syncthreads();

  // ---- h phase: wave w handles rows w*8..w*8+7, 8 lanes per row
  int tl = (w << 3) | (lane >> 3);         // 0..31
  int d8 = (lane & 7) * 8;
  int t = t0 + tl;
  int row = t*4 + b;
  float dn = __expf(rowt[bh*512 + t]) * qsS[tl]
           + denS[tl][0] + denS[tl][1] + denS[tl][2] + denS[tl][3];
  dn = fmaxf(fabsf(dn), 1.f);
  short8 ovh = *(const short8*)(c3h + (size_t)row*N3 + 512 + h*64 + d8);
  short8 ovl = *(const short8*)(c3l + (size_t)row*N3 + 512 + h*64 + d8);
  float hv[8], s_ = 0.f, ss = 0.f;
  for (int e=0;e<8;e++){
    float ov = bfbits2f(ovh[e]) + bfbits2f(ovl[e]);
    float o = 1.f/(1.f + __expf(-ov));
    float v = o * numS[tl][d8+e] / dn;
    hv[e] = v; s_ += v; ss += v*v;
  }
  s_ += __shfl_xor(s_,1); ss += __shfl_xor(ss,1);
  s_ += __shfl_xor(s_,2); ss += __shfl_xor(ss,2);
  s_ += __shfl_xor(s_,4); ss += __shfl_xor(ss,4);
  float mu = s_*(1.f/64.f), var = ss*(1.f/64.f) - mu*mu;
  float rs = rsqrtf(var + EPSV);
  short8 skh = *(const short8*)(c2h + (size_t)row*N2 + 1024 + h*64 + d8);
  short8 skl = *(const short8*)(c2l + (size_t)row*N2 + 1024 + h*64 + d8);
  short8 rvh = *(const short8*)(c1h + (size_t)row*N1 + 1024 + h*64 + d8);
  short8 rvl = *(const short8*)(c1l + (size_t)row*N1 + 1024 + h*64 + d8);
  short8 yh, yl;
  for (int e=0;e<8;e++){
    float gn = (hv[e]-mu)*rs*gng[h*64+d8+e] + gnb[h*64+d8+e];
    float sk = bfbits2f(skh[e]) + bfbits2f(skl[e]);
    float rv = bfbits2f(rvh[e]) + bfbits2f(rvl[e]);
    float y = (gn + sk) * (rv/(1.f + __expf(-rv)));
    bf16 h_, l_;
    split_bf(y, h_, l_);
    yh[e] = *(short*)&h_; yl[e] = *(short*)&l_;
  }
  size_t oo = (size_t)row*512 + h*64 + d8;
  *(short8*)(oph+oo) = yh;
  *(short8*)(opl+oo) = yl;
}

// ===================== host =====================
extern "C" void kernel_launch(void* const* d_in, const int* in_sizes, int n_in,
                              void* d_out, int out_size, void* d_ws, size_t ws_size,
                              hipStream_t stream)
{
  (void)in_sizes; (void)n_in; (void)out_size; (void)ws_size;
  const float* seq    = (const float*)d_in[0];
  const float* ln_g   = (const float*)d_in[1];
  const float* ln_b   = (const float*)d_in[2];
  const float* upl_w  = (const float*)d_in[3];
  const float* upl_b  = (const float*)d_in[4];
  const float* upr_w  = (const float*)d_in[5];
  const float* upr_b  = (const float*)d_in[6];
  const float* conv_w = (const float*)d_in[7];
  const float* conv_b = (const float*)d_in[8];
  const float* wq_w   = (const float*)d_in[9];
  const float* wq_b   = (const float*)d_in[10];
  const float* wk_w   = (const float*)d_in[11];
  const float* wk_b   = (const float*)d_in[12];
  const float* wv_w   = (const float*)d_in[13];
  const float* wv_b   = (const float*)d_in[14];
  const float* wo_w   = (const float*)d_in[15];
  const float* wo_b   = (const float*)d_in[16];
  const float* wi_w   = (const float*)d_in[17];
  const float* wi_b   = (const float*)d_in[18];
  const float* wf_w   = (const float*)d_in[19];
  const float* wf_b   = (const float*)d_in[20];
  const float* skip_w = (const float*)d_in[21];
  const float* gn_g   = (const float*)d_in[22];
  const float* gn_b   = (const float*)d_in[23];
  const float* down_w = (const float*)d_in[24];
  const float* down_b = (const float*)d_in[25];

  char* ws = (char*)d_ws;
  size_t off = 0;
  auto alloc = [&](size_t bytes)->char*{
    char* p = ws + off; off = (off + bytes + 255) & ~(size_t)255; return p;
  };
  bf16*  W1h = (bf16*)alloc((size_t)3*N1*512*2);
  bf16*  W1l = (bf16*)alloc((size_t)3*N1*512*2);
  bf16*  W2h = (bf16*)alloc((size_t)3*N2*1024*2);
  bf16*  W2l = (bf16*)alloc((size_t)3*N2*1024*2);
  bf16*  W3h = (bf16*)alloc((size_t)3*N3*1024*2);
  bf16*  W3l = (bf16*)alloc((size_t)3*N3*1024*2);
  bf16*  W4h = (bf16*)alloc((size_t)3*512*512*2);
  bf16*  W4l = (bf16*)alloc((size_t)3*512*512*2);
  float* b1  = (float*)alloc((size_t)3*N1*4);
  float* b2  = (float*)alloc((size_t)3*N2*4);
  float* b3  = (float*)alloc((size_t)3*N3*4);
  float* b4  = (float*)alloc((size_t)3*512*4);
  bf16*  xnh = (bf16*)alloc((size_t)NROW*512*2);
  bf16*  xnl = (bf16*)alloc((size_t)NROW*512*2);
  bf16*  c1h = (bf16*)alloc((size_t)NROW*N1*2);
  bf16*  c1l = (bf16*)alloc((size_t)NROW*N1*2);
  bf16*  xch = (bf16*)alloc((size_t)NROW*1024*2);
  bf16*  xcl = (bf16*)alloc((size_t)NROW*1024*2);
  bf16*  c2h = (bf16*)alloc((size_t)NROW*N2*2);
  bf16*  c2l = (bf16*)alloc((size_t)NROW*N2*2);
  bf16*  c3h = (bf16*)alloc((size_t)NROW*N3*2);
  bf16*  c3l = (bf16*)alloc((size_t)NROW*N3*2);
  bf16*  vTh = (bf16*)alloc((size_t)32*64*512*2);
  bf16*  vTl = (bf16*)alloc((size_t)32*64*512*2);
  float* rowt= (float*)alloc((size_t)32*512*4);
  float* colt= (float*)alloc((size_t)32*512*4);
  bf16*  oph = (bf16*)alloc((size_t)NROW*512*2);
  bf16*  opl = (bf16*)alloc((size_t)NROW*512*2);
  float* xA  = (float*)alloc((size_t)NROW*512*4);
  float* xB  = (float*)alloc((size_t)NROW*512*4);

  // --- pack all weights/biases to hi/lo bf16 (k-scale folded) in ONE dispatch ---
  pack_all<<<dim3(3713,3), 256, 0, stream>>>(
      upl_w, upr_w, wq_w, wk_w, skip_w, wi_w, wf_w, wv_w, wo_w, down_w,
      upl_b, upr_b, wq_b, wk_b, wi_b, wf_b, wv_b, wo_b, down_b,
      W1h, W1l, W2h, W2l, W3h, W3l, W4h, W4l, b1, b2, b3, b4);

  for (int l = 0; l < 3; l++){
    const float* x_in = (l == 0) ? seq : ((l == 1) ? xA : xB);
    float* x_out = (l == 0) ? xA : ((l == 1) ? xB : (float*)d_out);

    ln_kernel<<<NROW, 256, 0, stream>>>(x_in, ln_g + l*512, ln_b + l*512, xnh, xnl);
    gemm_s64<<<32*12, 256, 0, stream>>>(
        xnh, xnl, W1h + (size_t)l*N1*512, W1l + (size_t)l*N1*512,
        b1 + l*N1, nullptr, c1h, c1l, nullptr, N1, 512, 512, 12);
    conv_kernel<<<NROW, 256, 0, stream>>>(c1h, c1l, conv_w + l*4, conv_b + l,
                                          xch, xcl);
    gemm23<<<21*16, 512, 0, stream>>>(
        xch, xcl, W2h + (size_t)l*N2*1024, W2l + (size_t)l*N2*1024, b2 + l*N2,
        c2h, c2l,
        c1h, c1l, W3h + (size_t)l*N3*1024, W3l + (size_t)l*N3*1024, b3 + l*N3,
        c3h, c3l);
    prep_kernel<<<dim3(9,32), 512, 0, stream>>>(c3h, c3l, c2h, c2l,
                                                vTh, vTl, rowt, colt);
    attn_kernel<<<dim3(16,32), 256, 0, stream>>>(c2h, c2l, vTh, vTl,
                                                 rowt, colt, c3h, c3l, c1h, c1l,
                                                 gn_g + l*512, gn_b + l*512,
                                                 oph, opl);
    gemm_s64<<<32*4, 256, 0, stream>>>(
        oph, opl, W4h + (size_t)l*512*512, W4l + (size_t)l*512*512,
        b4 + l*512, x_out, nullptr, nullptr, x_in, 512, 512, 512, 4);
  }
}